// Round 2
// baseline (1119.130 us; speedup 1.0000x reference)
//
#include <hip/hip_runtime.h>
#include <math.h>

#define BB 8
#define LL 1024
#define DD 1024
#define NM 32     // complex modes per channel
#define NCH 16    // chunks over L
#define CL 64     // chunk length (NCH*CL == LL)

// ---------------- GEMM tile loader: 64 rows x 16 k, store transposed [k][row] ----
__device__ __forceinline__ void load_tile_T(const float* __restrict__ src,
                                            float (*dst)[68], int t)
{
    int r = t >> 2;
    int c4 = (t & 3) << 2;
    float4 q = *(const float4*)(src + (size_t)r * DD + c4);
    dst[c4 + 0][r] = q.x;
    dst[c4 + 1][r] = q.y;
    dst[c4 + 2][r] = q.z;
    dst[c4 + 3][r] = q.w;
}

// C[m,n] = sum_k A[m,k]*W[n,k] + bias[n]   (A,W both K-contiguous row-major)
__global__ __launch_bounds__(256)
void gemm_in_kernel(const float* __restrict__ x, const float* __restrict__ W,
                    const float* __restrict__ bias, float* __restrict__ out)
{
    __shared__ float As[16][68];
    __shared__ float Bs[16][68];
    const int t = threadIdx.x;
    const int m0 = blockIdx.y << 6;
    const int n0 = blockIdx.x << 6;
    const float* a = x + (size_t)m0 * DD;
    const float* w = W + (size_t)n0 * DD;
    float acc[4][4] = {};
    const int ty = t >> 4, tx = t & 15;
    for (int k0 = 0; k0 < DD; k0 += 16) {
        load_tile_T(a + k0, As, t);
        load_tile_T(w + k0, Bs, t);
        __syncthreads();
        #pragma unroll
        for (int k = 0; k < 16; ++k) {
            float4 a4 = *(const float4*)&As[k][ty << 2];
            float4 b4 = *(const float4*)&Bs[k][tx << 2];
            float av[4] = {a4.x, a4.y, a4.z, a4.w};
            float bv[4] = {b4.x, b4.y, b4.z, b4.w};
            #pragma unroll
            for (int i = 0; i < 4; ++i)
                #pragma unroll
                for (int j = 0; j < 4; ++j)
                    acc[i][j] = fmaf(av[i], bv[j], acc[i][j]);
        }
        __syncthreads();
    }
    #pragma unroll
    for (int i = 0; i < 4; ++i) {
        int m = m0 + (ty << 2) + i;
        int n = n0 + (tx << 2);
        float4 o;
        o.x = acc[i][0] + bias[n + 0];
        o.y = acc[i][1] + bias[n + 1];
        o.z = acc[i][2] + bias[n + 2];
        o.w = acc[i][3] + bias[n + 3];
        *(float4*)(out + (size_t)m * DD + n) = o;
    }
}

// GLU: za = yg@Wa^T + ba, zg = yg@Wg^T + bgc ; v = za*sigmoid(zg)
__global__ __launch_bounds__(256)
void gemm_glu_kernel(const float* __restrict__ yg, const float* __restrict__ Wg,
                     const float* __restrict__ bg, float* __restrict__ v)
{
    __shared__ float As[16][68];
    __shared__ float Ba[16][68];
    __shared__ float Bg[16][68];
    const int t = threadIdx.x;
    const int m0 = blockIdx.y << 6;
    const int n0 = blockIdx.x << 6;
    const float* a  = yg + (size_t)m0 * DD;
    const float* wa = Wg + (size_t)n0 * DD;
    const float* wg = Wg + ((size_t)n0 + DD) * DD;
    float aca[4][4] = {}, acg[4][4] = {};
    const int ty = t >> 4, tx = t & 15;
    for (int k0 = 0; k0 < DD; k0 += 16) {
        load_tile_T(a + k0, As, t);
        load_tile_T(wa + k0, Ba, t);
        load_tile_T(wg + k0, Bg, t);
        __syncthreads();
        #pragma unroll
        for (int k = 0; k < 16; ++k) {
            float4 a4  = *(const float4*)&As[k][ty << 2];
            float4 ba4 = *(const float4*)&Ba[k][tx << 2];
            float4 bg4 = *(const float4*)&Bg[k][tx << 2];
            float av[4]  = {a4.x, a4.y, a4.z, a4.w};
            float bav[4] = {ba4.x, ba4.y, ba4.z, ba4.w};
            float bgv[4] = {bg4.x, bg4.y, bg4.z, bg4.w};
            #pragma unroll
            for (int i = 0; i < 4; ++i)
                #pragma unroll
                for (int j = 0; j < 4; ++j) {
                    aca[i][j] = fmaf(av[i], bav[j], aca[i][j]);
                    acg[i][j] = fmaf(av[i], bgv[j], acg[i][j]);
                }
        }
        __syncthreads();
    }
    #pragma unroll
    for (int i = 0; i < 4; ++i) {
        int m = m0 + (ty << 2) + i;
        int n = n0 + (tx << 2);
        float o[4];
        #pragma unroll
        for (int j = 0; j < 4; ++j) {
            float za = aca[i][j] + bg[n + j];
            float zg = acg[i][j] + bg[DD + n + j];
            o[j] = za / (1.f + expf(-zg));
        }
        float4 o4 = {o[0], o[1], o[2], o[3]};
        *(float4*)(v + (size_t)m * DD + n) = o4;
    }
}

// out = v@W^T + bias + x   (residual)
__global__ __launch_bounds__(256)
void gemm_out_kernel(const float* __restrict__ vv, const float* __restrict__ W,
                     const float* __restrict__ bias, const float* __restrict__ xres,
                     float* __restrict__ out)
{
    __shared__ float As[16][68];
    __shared__ float Bs[16][68];
    const int t = threadIdx.x;
    const int m0 = blockIdx.y << 6;
    const int n0 = blockIdx.x << 6;
    const float* a = vv + (size_t)m0 * DD;
    const float* w = W + (size_t)n0 * DD;
    float acc[4][4] = {};
    const int ty = t >> 4, tx = t & 15;
    for (int k0 = 0; k0 < DD; k0 += 16) {
        load_tile_T(a + k0, As, t);
        load_tile_T(w + k0, Bs, t);
        __syncthreads();
        #pragma unroll
        for (int k = 0; k < 16; ++k) {
            float4 a4 = *(const float4*)&As[k][ty << 2];
            float4 b4 = *(const float4*)&Bs[k][tx << 2];
            float av[4] = {a4.x, a4.y, a4.z, a4.w};
            float bv[4] = {b4.x, b4.y, b4.z, b4.w};
            #pragma unroll
            for (int i = 0; i < 4; ++i)
                #pragma unroll
                for (int j = 0; j < 4; ++j)
                    acc[i][j] = fmaf(av[i], bv[j], acc[i][j]);
        }
        __syncthreads();
    }
    #pragma unroll
    for (int i = 0; i < 4; ++i) {
        int m = m0 + (ty << 2) + i;
        int n = n0 + (tx << 2);
        float4 xr = *(const float4*)(xres + (size_t)m * DD + n);
        float4 o;
        o.x = acc[i][0] + bias[n + 0] + xr.x;
        o.y = acc[i][1] + bias[n + 1] + xr.y;
        o.z = acc[i][2] + bias[n + 2] + xr.z;
        o.w = acc[i][3] + bias[n + 3] + xr.w;
        *(float4*)(out + (size_t)m * DD + n) = o;
    }
}

// ---------------- S4D scan: 2-pass chunked recurrence ----------------
// Pass A: per (b, chunk, h): chunk-local end state (zero init).
// S layout: [b][c][comp][h], comp = 2n (re) / 2n+1 (im)
__global__ __launch_bounds__(64)
void s4d_passA(const float* __restrict__ u, const float* __restrict__ log_dt,
               const float* __restrict__ lar, const float* __restrict__ aim,
               float* __restrict__ Sl)
{
    const int lane = threadIdx.x;
    const int h = (blockIdx.x << 6) + lane;
    const int c = blockIdx.y;
    const int b = blockIdx.z;
    const float dt = expf(log_dt[h]);
    float wr[NM], wi[NM], sr[NM], si[NM];
    #pragma unroll
    for (int n = 0; n < NM; ++n) {
        float ar = -expf(lar[h * NM + n]);
        float ai = aim[h * NM + n];
        float sn, cs;
        sincosf(ai * dt, &sn, &cs);
        float er = expf(ar * dt);
        wr[n] = er * cs; wi[n] = er * sn;
        sr[n] = 0.f; si[n] = 0.f;
    }
    const float* up = u + ((size_t)b * LL + (size_t)c * CL) * DD + h;
    float uc = up[0];
    for (int l = 0; l < CL; ++l) {
        float un = (l + 1 < CL) ? up[(size_t)(l + 1) * DD] : 0.f;
        #pragma unroll
        for (int n = 0; n < NM; ++n) {
            float t0 = fmaf(wr[n], sr[n], uc);
            t0 = fmaf(-wi[n], si[n], t0);
            si[n] = fmaf(wr[n], si[n], wi[n] * sr[n]);
            sr[n] = t0;
        }
        uc = un;
    }
    float* sp = Sl + (((size_t)b * NCH + c) * (2 * NM)) * DD + h;
    #pragma unroll
    for (int n = 0; n < NM; ++n) {
        sp[(size_t)(2 * n) * DD]     = sr[n];
        sp[(size_t)(2 * n + 1) * DD] = si[n];
    }
}

// Pass B: sequential combine across chunks (in place: Sloc -> carry-in states)
__global__ __launch_bounds__(64)
void s4d_passB(float* __restrict__ S, const float* __restrict__ log_dt,
               const float* __restrict__ lar, const float* __restrict__ aim)
{
    const int lane = threadIdx.x;
    const int h = (blockIdx.x << 6) + lane;
    const int b = blockIdx.y;
    const float dt = expf(log_dt[h]);
    float gr[NM], gi[NM], sr[NM], si[NM];
    #pragma unroll
    for (int n = 0; n < NM; ++n) {
        float ar = -expf(lar[h * NM + n]);
        float ai = aim[h * NM + n];
        float sn, cs;
        sincosf(ai * dt * (float)CL, &sn, &cs);
        float er = expf(ar * dt * (float)CL);
        gr[n] = er * cs; gi[n] = er * sn;
        sr[n] = 0.f; si[n] = 0.f;
    }
    for (int c = 0; c < NCH; ++c) {
        float* sp = S + (((size_t)b * NCH + c) * (2 * NM)) * DD + h;
        #pragma unroll
        for (int n = 0; n < NM; ++n) {
            float lr = sp[(size_t)(2 * n) * DD];
            float li = sp[(size_t)(2 * n + 1) * DD];
            sp[(size_t)(2 * n) * DD]     = sr[n];   // carry-in state for chunk c
            sp[(size_t)(2 * n + 1) * DD] = si[n];
            float t0 = fmaf(gr[n], sr[n], lr);
            t0 = fmaf(-gi[n], si[n], t0);
            si[n] = fmaf(gr[n], si[n], fmaf(gi[n], sr[n], li));
            sr[n] = t0;
        }
    }
}

// Pass C: emit y = gelu(conv + D_skip*u) in place over u  (u -> ygelu)
__global__ __launch_bounds__(64)
void s4d_passC(float* uy, const float* __restrict__ S,
               const float* __restrict__ log_dt, const float* __restrict__ lar,
               const float* __restrict__ aim, const float* __restrict__ Cp,
               const float* __restrict__ dskip)
{
    const int lane = threadIdx.x;
    const int h = (blockIdx.x << 6) + lane;
    const int c = blockIdx.y;
    const int b = blockIdx.z;
    const float dt = expf(log_dt[h]);
    float wr[NM], wi[NM], cr[NM], ci[NM], sr[NM], si[NM];
    const float* sp = S + (((size_t)b * NCH + c) * (2 * NM)) * DD + h;
    #pragma unroll
    for (int n = 0; n < NM; ++n) {
        float ar = -expf(lar[h * NM + n]);
        float ai = aim[h * NM + n];
        float sn, cs;
        sincosf(ai * dt, &sn, &cs);
        float er = expf(ar * dt);
        float wrr = er * cs, wii = er * sn;
        wr[n] = wrr; wi[n] = wii;
        float Crr = Cp[(h * NM + n) * 2 + 0];
        float Cii = Cp[(h * NM + n) * 2 + 1];
        // Ceff*2 = 2*(Cr+iCi)*((w-1))/A,  A = ar + i*ai
        float nr = fmaf(Crr, wrr - 1.f, -Cii * wii);
        float ni = fmaf(Crr, wii, Cii * (wrr - 1.f));
        float inv = 2.f / fmaf(ar, ar, ai * ai);
        cr[n] = fmaf(nr, ar, ni * ai) * inv;
        ci[n] = fmaf(ni, ar, -nr * ai) * inv;
        sr[n] = sp[(size_t)(2 * n) * DD];
        si[n] = sp[(size_t)(2 * n + 1) * DD];
    }
    const float dk = dskip[h];
    float* up = uy + ((size_t)b * LL + (size_t)c * CL) * DD + h;
    float uc = up[0];
    for (int l = 0; l < CL; ++l) {
        float un = (l + 1 < CL) ? up[(size_t)(l + 1) * DD] : 0.f;
        float y = dk * uc;
        #pragma unroll
        for (int n = 0; n < NM; ++n) {
            float t0 = fmaf(wr[n], sr[n], uc);
            t0 = fmaf(-wi[n], si[n], t0);
            si[n] = fmaf(wr[n], si[n], wi[n] * sr[n]);
            sr[n] = t0;
            y = fmaf(cr[n], sr[n], y);
            y = fmaf(-ci[n], si[n], y);
        }
        y = 0.5f * y * (1.f + erff(y * 0.70710678118654752f));
        up[(size_t)l * DD] = y;
        uc = un;
    }
}

extern "C" void kernel_launch(void* const* d_in, const int* in_sizes, int n_in,
                              void* d_out, int out_size, void* d_ws, size_t ws_size,
                              hipStream_t stream)
{
    (void)in_sizes; (void)n_in; (void)out_size; (void)ws_size;
    const float* x      = (const float*)d_in[0];
    const float* in_W   = (const float*)d_in[1];
    const float* in_b   = (const float*)d_in[2];
    const float* log_dt = (const float*)d_in[3];
    const float* Cp     = (const float*)d_in[4];
    const float* lar    = (const float*)d_in[5];
    const float* aim    = (const float*)d_in[6];
    const float* dsk    = (const float*)d_in[7];
    const float* gluW   = (const float*)d_in[8];
    const float* glub   = (const float*)d_in[9];
    const float* outW   = (const float*)d_in[10];
    const float* outb   = (const float*)d_in[11];

    // d_out (B*L*D floats) doubles as the u / gelu(y) buffer until the final GEMM.
    // d_ws only holds S (chunk states, 33.5 MiB), later aliased by the GLU output v.
    float* u = (float*)d_out;                       // (B,L,D); becomes ygelu in place
    float* S = (float*)d_ws;                        // chunk states: B*NCH*64*D floats
    float* v = S;                                   // GLU output aliases S (S dead by then)

    dim3 gblk(256), gemm_grid(16, 128, 1);
    gemm_in_kernel <<<gemm_grid, gblk, 0, stream>>>(x, in_W, in_b, u);
    s4d_passA      <<<dim3(DD / 64, NCH, BB), dim3(64), 0, stream>>>(u, log_dt, lar, aim, S);
    s4d_passB      <<<dim3(DD / 64, BB),      dim3(64), 0, stream>>>(S, log_dt, lar, aim);
    s4d_passC      <<<dim3(DD / 64, NCH, BB), dim3(64), 0, stream>>>(u, S, log_dt, lar, aim, Cp, dsk);
    gemm_glu_kernel<<<gemm_grid, gblk, 0, stream>>>(u, gluW, glub, v);
    gemm_out_kernel<<<gemm_grid, gblk, 0, stream>>>(v, outW, outb, x, (float*)d_out);
}

// Round 3
// 452.598 us; speedup vs baseline: 2.4727x; 2.4727x over previous
//
#include <hip/hip_runtime.h>
#include <math.h>

#define BB 8
#define LL 1024
#define DD 1024
#define KD 1024   // GEMM K depth (all three GEMMs)
#define NM 32     // complex modes per channel
#define NCH 16    // chunks over L
#define CL 64     // chunk length (NCH*CL == LL)

typedef __bf16 bf16_t;
typedef __bf16 bf16x8 __attribute__((ext_vector_type(8)));
typedef __bf16 bf16x4 __attribute__((ext_vector_type(4)));
typedef float  f32x4  __attribute__((ext_vector_type(4)));

// ---------------- fp32 -> bf16 convert (RTN) ----------------
__global__ __launch_bounds__(256)
void f2b_kernel(const float* __restrict__ s, bf16_t* __restrict__ d, int n)
{
    int i = (blockIdx.x * 256 + threadIdx.x) * 4;
    if (i < n) {
        float4 f = *(const float4*)(s + i);
        bf16x4 o = { (bf16_t)f.x, (bf16_t)f.y, (bf16_t)f.z, (bf16_t)f.w };
        *(bf16x4*)(d + i) = o;
    }
}

// ---------------- global->LDS staging: 128 rows x 32 bf16 (K-contiguous) ------
// LDS layout: row-major [128][32], 64 B/row. Lane-contiguity requirement of
// global_load_lds holds: per wave w, issue q, LDS off = q*4096 + w*1024 + lane*16.
__device__ __forceinline__ void stage128x32(const bf16_t* __restrict__ g,
                                            bf16_t* lds, int tid)
{
    #pragma unroll
    for (int q = 0; q < 2; ++q) {
        const bf16_t* src = g + (size_t)(q * 64 + (tid >> 2)) * KD + (tid & 3) * 8;
        bf16_t* dst = lds + q * 2048 + tid * 8;
        __builtin_amdgcn_global_load_lds(
            (const __attribute__((address_space(1))) void*)src,
            (__attribute__((address_space(3))) void*)dst, 16, 0, 0);
    }
}

// ---------------- bf16 MFMA GEMM: C[m,n] = sum_k A[m,k]*W[n,k] (+epilogue) ----
// MODE 0: out fp32 = acc + bias          (in-proj)
// MODE 1: out fp32 = acc + bias + res    (out-proj + residual)
template<int MODE>
__global__ __launch_bounds__(256)
void gemm16_kernel(const bf16_t* __restrict__ A, const bf16_t* __restrict__ Wb,
                   const float* __restrict__ bias, const float* __restrict__ res,
                   float* __restrict__ out)
{
    __shared__ bf16_t As[128 * 32];
    __shared__ bf16_t Bs[128 * 32];
    const int tid = threadIdx.x;
    const int lane = tid & 63, w = tid >> 6;
    const int wy = w >> 1, wx = w & 1;
    const int m0 = blockIdx.y << 7, n0 = blockIdx.x << 7;
    const bf16_t* Ag = A  + (size_t)m0 * KD;
    const bf16_t* Bg = Wb + (size_t)n0 * KD;
    f32x4 acc[4][4] = {};
    const int lm = lane & 15;           // m (A-frag) / n (B-frag) within 16-tile
    const int ks = (lane >> 4) << 3;    // k offset within 32

    for (int k0 = 0; k0 < KD; k0 += 32) {
        stage128x32(Ag + k0, As, tid);
        stage128x32(Bg + k0, Bs, tid);
        __syncthreads();
        bf16x8 af[4], bfr[4];
        #pragma unroll
        for (int i = 0; i < 4; ++i)
            af[i] = *(bf16x8*)&As[((wy << 6) + (i << 4) + lm) * 32 + ks];
        #pragma unroll
        for (int j = 0; j < 4; ++j)
            bfr[j] = *(bf16x8*)&Bs[((wx << 6) + (j << 4) + lm) * 32 + ks];
        #pragma unroll
        for (int i = 0; i < 4; ++i)
            #pragma unroll
            for (int j = 0; j < 4; ++j)
                acc[i][j] = __builtin_amdgcn_mfma_f32_16x16x32_bf16(
                                af[i], bfr[j], acc[i][j], 0, 0, 0);
        __syncthreads();
    }

    const int row4 = (lane >> 4) << 2;
    #pragma unroll
    for (int i = 0; i < 4; ++i) {
        #pragma unroll
        for (int r = 0; r < 4; ++r) {
            int m = m0 + (wy << 6) + (i << 4) + row4 + r;
            #pragma unroll
            for (int j = 0; j < 4; ++j) {
                int n = n0 + (wx << 6) + (j << 4) + lm;
                float v = acc[i][j][r] + bias[n];
                if (MODE == 1) v += res[(size_t)m * DD + n];
                out[(size_t)m * DD + n] = v;
            }
        }
    }
}

// ---------------- fused GLU GEMM: za=y@Wa^T+ba, zg=y@Wg^T+bg ; v=za*sig(zg) ---
__global__ __launch_bounds__(256)
void gemm_glu16_kernel(const bf16_t* __restrict__ A, const bf16_t* __restrict__ Wb,
                       const float* __restrict__ bias, bf16_t* __restrict__ vout)
{
    __shared__ bf16_t As[128 * 32];
    __shared__ bf16_t Ba[128 * 32];
    __shared__ bf16_t Bg[128 * 32];
    const int tid = threadIdx.x;
    const int lane = tid & 63, w = tid >> 6;
    const int wy = w >> 1, wx = w & 1;
    const int m0 = blockIdx.y << 7, n0 = blockIdx.x << 7;
    const bf16_t* Ag  = A  + (size_t)m0 * KD;
    const bf16_t* Bga = Wb + (size_t)n0 * KD;
    const bf16_t* Bgg = Wb + ((size_t)n0 + DD) * KD;
    f32x4 aca[4][4] = {}, acg[4][4] = {};
    const int lm = lane & 15;
    const int ks = (lane >> 4) << 3;

    for (int k0 = 0; k0 < KD; k0 += 32) {
        stage128x32(Ag  + k0, As, tid);
        stage128x32(Bga + k0, Ba, tid);
        stage128x32(Bgg + k0, Bg, tid);
        __syncthreads();
        bf16x8 af[4];
        #pragma unroll
        for (int i = 0; i < 4; ++i)
            af[i] = *(bf16x8*)&As[((wy << 6) + (i << 4) + lm) * 32 + ks];
        #pragma unroll
        for (int j = 0; j < 4; ++j) {
            bf16x8 ba = *(bf16x8*)&Ba[((wx << 6) + (j << 4) + lm) * 32 + ks];
            bf16x8 bg = *(bf16x8*)&Bg[((wx << 6) + (j << 4) + lm) * 32 + ks];
            #pragma unroll
            for (int i = 0; i < 4; ++i) {
                aca[i][j] = __builtin_amdgcn_mfma_f32_16x16x32_bf16(af[i], ba, aca[i][j], 0, 0, 0);
                acg[i][j] = __builtin_amdgcn_mfma_f32_16x16x32_bf16(af[i], bg, acg[i][j], 0, 0, 0);
            }
        }
        __syncthreads();
    }

    const int row4 = (lane >> 4) << 2;
    #pragma unroll
    for (int i = 0; i < 4; ++i) {
        #pragma unroll
        for (int r = 0; r < 4; ++r) {
            int m = m0 + (wy << 6) + (i << 4) + row4 + r;
            #pragma unroll
            for (int j = 0; j < 4; ++j) {
                int n = n0 + (wx << 6) + (j << 4) + lm;
                float za = aca[i][j][r] + bias[n];
                float zg = acg[i][j][r] + bias[DD + n];
                float v = za / (1.f + expf(-zg));
                vout[(size_t)m * DD + n] = (bf16_t)v;
            }
        }
    }
}

// ---------------- S4D scan: 2-pass chunked recurrence ----------------
__global__ __launch_bounds__(64)
void s4d_passA(const float* __restrict__ u, const float* __restrict__ log_dt,
               const float* __restrict__ lar, const float* __restrict__ aim,
               float* __restrict__ Sl)
{
    const int lane = threadIdx.x;
    const int h = (blockIdx.x << 6) + lane;
    const int c = blockIdx.y;
    const int b = blockIdx.z;
    const float dt = expf(log_dt[h]);
    float wr[NM], wi[NM], sr[NM], si[NM];
    #pragma unroll
    for (int n = 0; n < NM; ++n) {
        float ar = -expf(lar[h * NM + n]);
        float ai = aim[h * NM + n];
        float sn, cs;
        sincosf(ai * dt, &sn, &cs);
        float er = expf(ar * dt);
        wr[n] = er * cs; wi[n] = er * sn;
        sr[n] = 0.f; si[n] = 0.f;
    }
    const float* up = u + ((size_t)b * LL + (size_t)c * CL) * DD + h;
    float uc = up[0];
    for (int l = 0; l < CL; ++l) {
        float un = (l + 1 < CL) ? up[(size_t)(l + 1) * DD] : 0.f;
        #pragma unroll
        for (int n = 0; n < NM; ++n) {
            float t0 = fmaf(wr[n], sr[n], uc);
            t0 = fmaf(-wi[n], si[n], t0);
            si[n] = fmaf(wr[n], si[n], wi[n] * sr[n]);
            sr[n] = t0;
        }
        uc = un;
    }
    float* sp = Sl + (((size_t)b * NCH + c) * (2 * NM)) * DD + h;
    #pragma unroll
    for (int n = 0; n < NM; ++n) {
        sp[(size_t)(2 * n) * DD]     = sr[n];
        sp[(size_t)(2 * n + 1) * DD] = si[n];
    }
}

__global__ __launch_bounds__(64)
void s4d_passB(float* __restrict__ S, const float* __restrict__ log_dt,
               const float* __restrict__ lar, const float* __restrict__ aim)
{
    const int lane = threadIdx.x;
    const int h = (blockIdx.x << 6) + lane;
    const int b = blockIdx.y;
    const float dt = expf(log_dt[h]);
    float gr[NM], gi[NM], sr[NM], si[NM];
    #pragma unroll
    for (int n = 0; n < NM; ++n) {
        float ar = -expf(lar[h * NM + n]);
        float ai = aim[h * NM + n];
        float sn, cs;
        sincosf(ai * dt * (float)CL, &sn, &cs);
        float er = expf(ar * dt * (float)CL);
        gr[n] = er * cs; gi[n] = er * sn;
        sr[n] = 0.f; si[n] = 0.f;
    }
    for (int c = 0; c < NCH; ++c) {
        float* sp = S + (((size_t)b * NCH + c) * (2 * NM)) * DD + h;
        #pragma unroll
        for (int n = 0; n < NM; ++n) {
            float lr = sp[(size_t)(2 * n) * DD];
            float li = sp[(size_t)(2 * n + 1) * DD];
            sp[(size_t)(2 * n) * DD]     = sr[n];   // carry-in state for chunk c
            sp[(size_t)(2 * n + 1) * DD] = si[n];
            float t0 = fmaf(gr[n], sr[n], lr);
            t0 = fmaf(-gi[n], si[n], t0);
            si[n] = fmaf(gr[n], si[n], fmaf(gi[n], sr[n], li));
            sr[n] = t0;
        }
    }
}

// Pass C: y = gelu(conv + D_skip*u), written as bf16 (A-operand of GLU GEMM)
__global__ __launch_bounds__(64)
void s4d_passC(const float* __restrict__ u, bf16_t* __restrict__ yb,
               const float* __restrict__ S,
               const float* __restrict__ log_dt, const float* __restrict__ lar,
               const float* __restrict__ aim, const float* __restrict__ Cp,
               const float* __restrict__ dskip)
{
    const int lane = threadIdx.x;
    const int h = (blockIdx.x << 6) + lane;
    const int c = blockIdx.y;
    const int b = blockIdx.z;
    const float dt = expf(log_dt[h]);
    float wr[NM], wi[NM], cr[NM], ci[NM], sr[NM], si[NM];
    const float* sp = S + (((size_t)b * NCH + c) * (2 * NM)) * DD + h;
    #pragma unroll
    for (int n = 0; n < NM; ++n) {
        float ar = -expf(lar[h * NM + n]);
        float ai = aim[h * NM + n];
        float sn, cs;
        sincosf(ai * dt, &sn, &cs);
        float er = expf(ar * dt);
        float wrr = er * cs, wii = er * sn;
        wr[n] = wrr; wi[n] = wii;
        float Crr = Cp[(h * NM + n) * 2 + 0];
        float Cii = Cp[(h * NM + n) * 2 + 1];
        float nr = fmaf(Crr, wrr - 1.f, -Cii * wii);
        float ni = fmaf(Crr, wii, Cii * (wrr - 1.f));
        float inv = 2.f / fmaf(ar, ar, ai * ai);
        cr[n] = fmaf(nr, ar, ni * ai) * inv;
        ci[n] = fmaf(ni, ar, -nr * ai) * inv;
        sr[n] = sp[(size_t)(2 * n) * DD];
        si[n] = sp[(size_t)(2 * n + 1) * DD];
    }
    const float dk = dskip[h];
    const float* up = u + ((size_t)b * LL + (size_t)c * CL) * DD + h;
    bf16_t* yp = yb + ((size_t)b * LL + (size_t)c * CL) * DD + h;
    float uc = up[0];
    for (int l = 0; l < CL; ++l) {
        float un = (l + 1 < CL) ? up[(size_t)(l + 1) * DD] : 0.f;
        float y = dk * uc;
        #pragma unroll
        for (int n = 0; n < NM; ++n) {
            float t0 = fmaf(wr[n], sr[n], uc);
            t0 = fmaf(-wi[n], si[n], t0);
            si[n] = fmaf(wr[n], si[n], wi[n] * sr[n]);
            sr[n] = t0;
            y = fmaf(cr[n], sr[n], y);
            y = fmaf(-ci[n], si[n], y);
        }
        y = 0.5f * y * (1.f + erff(y * 0.70710678118654752f));
        yp[(size_t)l * DD] = (bf16_t)y;
        uc = un;
    }
}

extern "C" void kernel_launch(void* const* d_in, const int* in_sizes, int n_in,
                              void* d_out, int out_size, void* d_ws, size_t ws_size,
                              hipStream_t stream)
{
    (void)in_sizes; (void)n_in; (void)out_size; (void)ws_size;
    const float* x      = (const float*)d_in[0];
    const float* in_W   = (const float*)d_in[1];
    const float* in_b   = (const float*)d_in[2];
    const float* log_dt = (const float*)d_in[3];
    const float* Cp     = (const float*)d_in[4];
    const float* lar    = (const float*)d_in[5];
    const float* aim    = (const float*)d_in[6];
    const float* dsk    = (const float*)d_in[7];
    const float* gluW   = (const float*)d_in[8];
    const float* glub   = (const float*)d_in[9];
    const float* outW   = (const float*)d_in[10];
    const float* outb   = (const float*)d_in[11];

    const int NTOK = BB * LL;                 // 8192 rows
    // ws layout (56 MiB total; keep under 64 MiB):
    //  [0,32M)    S (fp32 chunk states)  -- aliased by vb (bf16 GLU out) after passC
    //  [32M,48M)  xb (bf16 x)            -- aliased by yb (bf16 gelu out) after gemm_in
    //  [48M,50M)  wbin   [50M,54M) wbglu   [54M,56M) wbout
    char* ws = (char*)d_ws;
    float*  S     = (float*)(ws);
    bf16_t* vb    = (bf16_t*)(ws);
    bf16_t* xb    = (bf16_t*)(ws + (33554432));
    bf16_t* yb    = xb;
    bf16_t* wbin  = (bf16_t*)(ws + (50331648));
    bf16_t* wbglu = (bf16_t*)(ws + (52428800));
    bf16_t* wbout = (bf16_t*)(ws + (56623104));
    float*  u     = (float*)d_out;            // u / ygelu staging lives in d_out

    // fp32 -> bf16 converts
    f2b_kernel<<<dim3(NTOK * DD / 1024), dim3(256), 0, stream>>>(x,    xb,    NTOK * DD);
    f2b_kernel<<<dim3(DD * DD / 1024),   dim3(256), 0, stream>>>(in_W, wbin,  DD * DD);
    f2b_kernel<<<dim3(2 * DD * DD / 1024), dim3(256), 0, stream>>>(gluW, wbglu, 2 * DD * DD);
    f2b_kernel<<<dim3(DD * DD / 1024),   dim3(256), 0, stream>>>(outW, wbout, DD * DD);

    dim3 gblk(256), ggrid(DD / 128, NTOK / 128);
    gemm16_kernel<0><<<ggrid, gblk, 0, stream>>>(xb, wbin, in_b, nullptr, u);
    s4d_passA<<<dim3(DD / 64, NCH, BB), dim3(64), 0, stream>>>(u, log_dt, lar, aim, S);
    s4d_passB<<<dim3(DD / 64, BB),      dim3(64), 0, stream>>>(S, log_dt, lar, aim);
    s4d_passC<<<dim3(DD / 64, NCH, BB), dim3(64), 0, stream>>>(u, yb, S, log_dt, lar, aim, Cp, dsk);
    gemm_glu16_kernel<<<ggrid, gblk, 0, stream>>>(yb, wbglu, glub, vb);
    gemm16_kernel<1><<<ggrid, gblk, 0, stream>>>(vb, wbout, outb, x, (float*)d_out);
}

// Round 4
// 426.347 us; speedup vs baseline: 2.6249x; 1.0616x over previous
//
#include <hip/hip_runtime.h>
#include <math.h>

#define BB 8
#define LL 1024
#define DD 1024
#define KD 1024   // GEMM K depth (all three GEMMs)
#define NM 32     // complex modes per channel
#define NCH 16    // chunks over L
#define CL 64     // chunk length (NCH*CL == LL)

typedef __bf16 bf16_t;
typedef __bf16 bf16x8 __attribute__((ext_vector_type(8)));
typedef __bf16 bf16x4 __attribute__((ext_vector_type(4)));
typedef float  f32x4  __attribute__((ext_vector_type(4)));

// ---------------- fp32 -> bf16 convert (RTN) ----------------
__global__ __launch_bounds__(256)
void f2b_kernel(const float* __restrict__ s, bf16_t* __restrict__ d, int n)
{
    int i = (blockIdx.x * 256 + threadIdx.x) * 4;
    if (i < n) {
        float4 f = *(const float4*)(s + i);
        bf16x4 o = { (bf16_t)f.x, (bf16_t)f.y, (bf16_t)f.z, (bf16_t)f.w };
        *(bf16x4*)(d + i) = o;
    }
}

// ---------------- global->LDS staging: 128 rows x 32 bf16 (K-contiguous) ------
__device__ __forceinline__ void stage128x32(const bf16_t* __restrict__ g,
                                            bf16_t* lds, int tid)
{
    #pragma unroll
    for (int q = 0; q < 2; ++q) {
        const bf16_t* src = g + (size_t)(q * 64 + (tid >> 2)) * KD + (tid & 3) * 8;
        bf16_t* dst = lds + q * 2048 + tid * 8;
        __builtin_amdgcn_global_load_lds(
            (const __attribute__((address_space(1))) void*)src,
            (__attribute__((address_space(3))) void*)dst, 16, 0, 0);
    }
}

// ---------------- bf16 MFMA GEMM: C[m,n] = sum_k A[m,k]*W[n,k] (+epilogue) ----
// MODE 0: out fp32 = acc + bias          (in-proj)
// MODE 1: out fp32 = acc + bias + res    (out-proj + residual)
template<int MODE>
__global__ __launch_bounds__(256)
void gemm16_kernel(const bf16_t* __restrict__ A, const bf16_t* __restrict__ Wb,
                   const float* __restrict__ bias, const float* __restrict__ res,
                   float* __restrict__ out)
{
    __shared__ bf16_t As[128 * 32];
    __shared__ bf16_t Bs[128 * 32];
    const int tid = threadIdx.x;
    const int lane = tid & 63, w = tid >> 6;
    const int wy = w >> 1, wx = w & 1;
    const int m0 = blockIdx.y << 7, n0 = blockIdx.x << 7;
    const bf16_t* Ag = A  + (size_t)m0 * KD;
    const bf16_t* Bg = Wb + (size_t)n0 * KD;
    f32x4 acc[4][4] = {};
    const int lm = lane & 15;           // m (A-frag) / n (B-frag) within 16-tile
    const int ks = (lane >> 4) << 3;    // k offset within 32

    for (int k0 = 0; k0 < KD; k0 += 32) {
        stage128x32(Ag + k0, As, tid);
        stage128x32(Bg + k0, Bs, tid);
        __syncthreads();
        bf16x8 af[4], bfr[4];
        #pragma unroll
        for (int i = 0; i < 4; ++i)
            af[i] = *(bf16x8*)&As[((wy << 6) + (i << 4) + lm) * 32 + ks];
        #pragma unroll
        for (int j = 0; j < 4; ++j)
            bfr[j] = *(bf16x8*)&Bs[((wx << 6) + (j << 4) + lm) * 32 + ks];
        #pragma unroll
        for (int i = 0; i < 4; ++i)
            #pragma unroll
            for (int j = 0; j < 4; ++j)
                acc[i][j] = __builtin_amdgcn_mfma_f32_16x16x32_bf16(
                                af[i], bfr[j], acc[i][j], 0, 0, 0);
        __syncthreads();
    }

    const int row4 = (lane >> 4) << 2;
    #pragma unroll
    for (int i = 0; i < 4; ++i) {
        #pragma unroll
        for (int r = 0; r < 4; ++r) {
            int m = m0 + (wy << 6) + (i << 4) + row4 + r;
            #pragma unroll
            for (int j = 0; j < 4; ++j) {
                int n = n0 + (wx << 6) + (j << 4) + lm;
                float v = acc[i][j][r] + bias[n];
                if (MODE == 1) v += res[(size_t)m * DD + n];
                out[(size_t)m * DD + n] = v;
            }
        }
    }
}

// ---------------- fused GLU GEMM: za=y@Wa^T+ba, zg=y@Wg^T+bg ; v=za*sig(zg) ---
__global__ __launch_bounds__(256)
void gemm_glu16_kernel(const bf16_t* __restrict__ A, const bf16_t* __restrict__ Wb,
                       const float* __restrict__ bias, bf16_t* __restrict__ vout)
{
    __shared__ bf16_t As[128 * 32];
    __shared__ bf16_t Ba[128 * 32];
    __shared__ bf16_t Bg[128 * 32];
    const int tid = threadIdx.x;
    const int lane = tid & 63, w = tid >> 6;
    const int wy = w >> 1, wx = w & 1;
    const int m0 = blockIdx.y << 7, n0 = blockIdx.x << 7;
    const bf16_t* Ag  = A  + (size_t)m0 * KD;
    const bf16_t* Bga = Wb + (size_t)n0 * KD;
    const bf16_t* Bgg = Wb + ((size_t)n0 + DD) * KD;
    f32x4 aca[4][4] = {}, acg[4][4] = {};
    const int lm = lane & 15;
    const int ks = (lane >> 4) << 3;

    for (int k0 = 0; k0 < KD; k0 += 32) {
        stage128x32(Ag  + k0, As, tid);
        stage128x32(Bga + k0, Ba, tid);
        stage128x32(Bgg + k0, Bg, tid);
        __syncthreads();
        bf16x8 af[4];
        #pragma unroll
        for (int i = 0; i < 4; ++i)
            af[i] = *(bf16x8*)&As[((wy << 6) + (i << 4) + lm) * 32 + ks];
        #pragma unroll
        for (int j = 0; j < 4; ++j) {
            bf16x8 ba = *(bf16x8*)&Ba[((wx << 6) + (j << 4) + lm) * 32 + ks];
            bf16x8 bg = *(bf16x8*)&Bg[((wx << 6) + (j << 4) + lm) * 32 + ks];
            #pragma unroll
            for (int i = 0; i < 4; ++i) {
                aca[i][j] = __builtin_amdgcn_mfma_f32_16x16x32_bf16(af[i], ba, aca[i][j], 0, 0, 0);
                acg[i][j] = __builtin_amdgcn_mfma_f32_16x16x32_bf16(af[i], bg, acg[i][j], 0, 0, 0);
            }
        }
        __syncthreads();
    }

    const int row4 = (lane >> 4) << 2;
    #pragma unroll
    for (int i = 0; i < 4; ++i) {
        #pragma unroll
        for (int r = 0; r < 4; ++r) {
            int m = m0 + (wy << 6) + (i << 4) + row4 + r;
            #pragma unroll
            for (int j = 0; j < 4; ++j) {
                int n = n0 + (wx << 6) + (j << 4) + lm;
                float za = aca[i][j][r] + bias[n];
                float zg = acg[i][j][r] + bias[DD + n];
                float v = za / (1.f + expf(-zg));
                vout[(size_t)m * DD + n] = (bf16_t)v;
            }
        }
    }
}

// ---------------- S4D scan: mode-split chunked recurrence ----------------
// Lane layout (per wave): ch = lane&15 (channel within 16-group), g = lane>>4
// (mode group, 8 modes each). Block = 256 threads = 4 waves = 64 channels.
// S layout: [b][c][comp][h], comp = 2n (re) / 2n+1 (im), n = g*8+j.

// Pass A: chunk-local end states (zero init).
__global__ __launch_bounds__(256)
void s4d_passA(const float* __restrict__ u, const float* __restrict__ log_dt,
               const float* __restrict__ lar, const float* __restrict__ aim,
               float* __restrict__ Sl)
{
    const int tid = threadIdx.x;
    const int lane = tid & 63, wv = tid >> 6;
    const int ch = lane & 15, g = lane >> 4;
    const int h = (blockIdx.x << 6) + (wv << 4) + ch;
    const int c = blockIdx.y, b = blockIdx.z;
    const float dt = expf(log_dt[h]);
    float wr[8], wi[8], sr[8], si[8];
    #pragma unroll
    for (int j = 0; j < 8; ++j) {
        int n = (g << 3) + j;
        float ar = -expf(lar[h * NM + n]);
        float ai = aim[h * NM + n];
        float sn, cs;
        sincosf(ai * dt, &sn, &cs);
        float er = expf(ar * dt);
        wr[j] = er * cs; wi[j] = er * sn;
        sr[j] = 0.f; si[j] = 0.f;
    }
    const float* up = u + ((size_t)b * LL + (size_t)c * CL) * DD + h;
    float uc = up[0];
    for (int l = 0; l < CL; ++l) {
        float un = (l + 1 < CL) ? up[(size_t)(l + 1) * DD] : 0.f;
        #pragma unroll
        for (int j = 0; j < 8; ++j) {
            float t0 = fmaf(wr[j], sr[j], uc);
            t0 = fmaf(-wi[j], si[j], t0);
            si[j] = fmaf(wr[j], si[j], wi[j] * sr[j]);
            sr[j] = t0;
        }
        uc = un;
    }
    float* sp = Sl + (((size_t)b * NCH + c) * (2 * NM)) * DD + h;
    #pragma unroll
    for (int j = 0; j < 8; ++j) {
        int n = (g << 3) + j;
        sp[(size_t)(2 * n) * DD]     = sr[j];
        sp[(size_t)(2 * n + 1) * DD] = si[j];
    }
}

// Pass B: sequential combine across chunks (in place: Sloc -> carry-in states)
__global__ __launch_bounds__(64)
void s4d_passB(float* __restrict__ S, const float* __restrict__ log_dt,
               const float* __restrict__ lar, const float* __restrict__ aim)
{
    const int lane = threadIdx.x;
    const int h = (blockIdx.x << 6) + lane;
    const int b = blockIdx.y;
    const float dt = expf(log_dt[h]);
    float gr[NM], gi[NM], sr[NM], si[NM];
    #pragma unroll
    for (int n = 0; n < NM; ++n) {
        float ar = -expf(lar[h * NM + n]);
        float ai = aim[h * NM + n];
        float sn, cs;
        sincosf(ai * dt * (float)CL, &sn, &cs);
        float er = expf(ar * dt * (float)CL);
        gr[n] = er * cs; gi[n] = er * sn;
        sr[n] = 0.f; si[n] = 0.f;
    }
    for (int c = 0; c < NCH; ++c) {
        float* sp = S + (((size_t)b * NCH + c) * (2 * NM)) * DD + h;
        #pragma unroll
        for (int n = 0; n < NM; ++n) {
            float lr = sp[(size_t)(2 * n) * DD];
            float li = sp[(size_t)(2 * n + 1) * DD];
            sp[(size_t)(2 * n) * DD]     = sr[n];   // carry-in state for chunk c
            sp[(size_t)(2 * n + 1) * DD] = si[n];
            float t0 = fmaf(gr[n], sr[n], lr);
            t0 = fmaf(-gi[n], si[n], t0);
            si[n] = fmaf(gr[n], si[n], fmaf(gi[n], sr[n], li));
            sr[n] = t0;
        }
    }
}

// Pass C: y = gelu(conv + D_skip*u), bf16 out. Mode-split + shfl reduction.
__global__ __launch_bounds__(256)
void s4d_passC(const float* __restrict__ u, bf16_t* __restrict__ yb,
               const float* __restrict__ S,
               const float* __restrict__ log_dt, const float* __restrict__ lar,
               const float* __restrict__ aim, const float* __restrict__ Cp,
               const float* __restrict__ dskip)
{
    const int tid = threadIdx.x;
    const int lane = tid & 63, wv = tid >> 6;
    const int ch = lane & 15, g = lane >> 4;
    const int h = (blockIdx.x << 6) + (wv << 4) + ch;
    const int c = blockIdx.y, b = blockIdx.z;
    const float dt = expf(log_dt[h]);
    float wr[8], wi[8], cr[8], ci[8], sr[8], si[8];
    const float* sp = S + (((size_t)b * NCH + c) * (2 * NM)) * DD + h;
    #pragma unroll
    for (int j = 0; j < 8; ++j) {
        int n = (g << 3) + j;
        float ar = -expf(lar[h * NM + n]);
        float ai = aim[h * NM + n];
        float sn, cs;
        sincosf(ai * dt, &sn, &cs);
        float er = expf(ar * dt);
        float wrr = er * cs, wii = er * sn;
        wr[j] = wrr; wi[j] = wii;
        float Crr = Cp[(h * NM + n) * 2 + 0];
        float Cii = Cp[(h * NM + n) * 2 + 1];
        float nr = fmaf(Crr, wrr - 1.f, -Cii * wii);
        float ni = fmaf(Crr, wii, Cii * (wrr - 1.f));
        float inv = 2.f / fmaf(ar, ar, ai * ai);
        cr[j] = fmaf(nr, ar, ni * ai) * inv;
        ci[j] = fmaf(ni, ar, -nr * ai) * inv;
        sr[j] = sp[(size_t)(2 * n) * DD];
        si[j] = sp[(size_t)(2 * n + 1) * DD];
    }
    const float dk = (g == 0) ? dskip[h] : 0.f;   // only group 0 adds the skip term
    const float* up = u + ((size_t)b * LL + (size_t)c * CL) * DD + h;
    bf16_t* yp = yb + ((size_t)b * LL + (size_t)c * CL) * DD + h;
    float uc = up[0];
    for (int l = 0; l < CL; ++l) {
        float un = (l + 1 < CL) ? up[(size_t)(l + 1) * DD] : 0.f;
        float y = dk * uc;
        #pragma unroll
        for (int j = 0; j < 8; ++j) {
            float t0 = fmaf(wr[j], sr[j], uc);
            t0 = fmaf(-wi[j], si[j], t0);
            si[j] = fmaf(wr[j], si[j], wi[j] * sr[j]);
            sr[j] = t0;
            y = fmaf(cr[j], sr[j], y);
            y = fmaf(-ci[j], si[j], y);
        }
        y += __shfl_xor(y, 16);
        y += __shfl_xor(y, 32);
        y = 0.5f * y * (1.f + erff(y * 0.70710678118654752f));
        if (g == 0) yp[(size_t)l * DD] = (bf16_t)y;
        uc = un;
    }
}

extern "C" void kernel_launch(void* const* d_in, const int* in_sizes, int n_in,
                              void* d_out, int out_size, void* d_ws, size_t ws_size,
                              hipStream_t stream)
{
    (void)in_sizes; (void)n_in; (void)out_size; (void)ws_size;
    const float* x      = (const float*)d_in[0];
    const float* in_W   = (const float*)d_in[1];
    const float* in_b   = (const float*)d_in[2];
    const float* log_dt = (const float*)d_in[3];
    const float* Cp     = (const float*)d_in[4];
    const float* lar    = (const float*)d_in[5];
    const float* aim    = (const float*)d_in[6];
    const float* dsk    = (const float*)d_in[7];
    const float* gluW   = (const float*)d_in[8];
    const float* glub   = (const float*)d_in[9];
    const float* outW   = (const float*)d_in[10];
    const float* outb   = (const float*)d_in[11];

    const int NTOK = BB * LL;                 // 8192 rows
    // ws layout (56 MiB total):
    //  [0,32M)    S (fp32 chunk states)  -- aliased by vb (bf16 GLU out) after passC
    //  [32M,48M)  xb (bf16 x)            -- aliased by yb (bf16 gelu out) after gemm_in
    //  [48M,50M)  wbin   [50M,54M) wbglu   [54M,56M) wbout
    char* ws = (char*)d_ws;
    float*  S     = (float*)(ws);
    bf16_t* vb    = (bf16_t*)(ws);
    bf16_t* xb    = (bf16_t*)(ws + (33554432));
    bf16_t* yb    = xb;
    bf16_t* wbin  = (bf16_t*)(ws + (50331648));
    bf16_t* wbglu = (bf16_t*)(ws + (52428800));
    bf16_t* wbout = (bf16_t*)(ws + (56623104));
    float*  u     = (float*)d_out;            // u staging lives in d_out

    // fp32 -> bf16 converts
    f2b_kernel<<<dim3(NTOK * DD / 1024), dim3(256), 0, stream>>>(x,    xb,    NTOK * DD);
    f2b_kernel<<<dim3(DD * DD / 1024),   dim3(256), 0, stream>>>(in_W, wbin,  DD * DD);
    f2b_kernel<<<dim3(2 * DD * DD / 1024), dim3(256), 0, stream>>>(gluW, wbglu, 2 * DD * DD);
    f2b_kernel<<<dim3(DD * DD / 1024),   dim3(256), 0, stream>>>(outW, wbout, DD * DD);

    dim3 gblk(256), ggrid(DD / 128, NTOK / 128);
    gemm16_kernel<0><<<ggrid, gblk, 0, stream>>>(xb, wbin, in_b, nullptr, u);
    s4d_passA<<<dim3(DD / 64, NCH, BB), dim3(256), 0, stream>>>(u, log_dt, lar, aim, S);
    s4d_passB<<<dim3(DD / 64, BB),      dim3(64),  0, stream>>>(S, log_dt, lar, aim);
    s4d_passC<<<dim3(DD / 64, NCH, BB), dim3(256), 0, stream>>>(u, yb, S, log_dt, lar, aim, Cp, dsk);
    gemm_glu16_kernel<<<ggrid, gblk, 0, stream>>>(yb, wbglu, glub, vb);
    gemm16_kernel<1><<<ggrid, gblk, 0, stream>>>(vb, wbout, outb, x, (float*)d_out);
}

// Round 5
// 339.154 us; speedup vs baseline: 3.2998x; 1.2571x over previous
//
#include <hip/hip_runtime.h>
#include <math.h>

#define BB 8
#define LL 1024
#define DD 1024
#define KD 1024   // GEMM K depth (token-space GEMMs)
#define NM 32     // complex modes per channel
#define NCH 16    // chunks over L
#define CL 64     // chunk length (NCH*CL == LL)
#define NBATCH 128  // BB*NCH

typedef __bf16 bf16_t;
typedef __bf16 bf16x8 __attribute__((ext_vector_type(8)));
typedef __bf16 bf16x4 __attribute__((ext_vector_type(4)));
typedef float  f32x4  __attribute__((ext_vector_type(4)));

__device__ __forceinline__ float gelu_f(float z)
{
    // tanh-form gelu via sigmoid: z*sigma(1.59577*(z+0.044715 z^3)); max dev vs erf ~2e-4
    float t = fmaf(0.044715f * z * z, z, z);
    return z / (1.f + expf(-1.5957691216f * t));
}

// ---------------- fp32 -> bf16 convert (RTN) ----------------
__global__ __launch_bounds__(256)
void f2b_kernel(const float* __restrict__ s, bf16_t* __restrict__ d, int n)
{
    int i = (blockIdx.x * 256 + threadIdx.x) * 4;
    if (i < n) {
        float4 f = *(const float4*)(s + i);
        bf16x4 o = { (bf16_t)f.x, (bf16_t)f.y, (bf16_t)f.z, (bf16_t)f.w };
        *(bf16x4*)(d + i) = o;
    }
}

// ---------------- global->LDS staging: 128 rows x 32 bf16 (K-contiguous) ------
__device__ __forceinline__ void stage128x32(const bf16_t* __restrict__ g,
                                            bf16_t* lds, int tid)
{
    #pragma unroll
    for (int q = 0; q < 2; ++q) {
        const bf16_t* src = g + (size_t)(q * 64 + (tid >> 2)) * KD + (tid & 3) * 8;
        bf16_t* dst = lds + q * 2048 + tid * 8;
        __builtin_amdgcn_global_load_lds(
            (const __attribute__((address_space(1))) void*)src,
            (__attribute__((address_space(3))) void*)dst, 16, 0, 0);
    }
}

// ---------------- out-proj GEMM: out = v@W^T + bias + res (fp32 out) ----------
__global__ __launch_bounds__(256)
void gemm_out_kernel(const bf16_t* __restrict__ A, const bf16_t* __restrict__ Wb,
                     const float* __restrict__ bias, const float* __restrict__ res,
                     float* __restrict__ out)
{
    __shared__ bf16_t As[128 * 32];
    __shared__ bf16_t Bs[128 * 32];
    const int tid = threadIdx.x;
    const int lane = tid & 63, w = tid >> 6;
    const int wy = w >> 1, wx = w & 1;
    const int m0 = blockIdx.y << 7, n0 = blockIdx.x << 7;
    const bf16_t* Ag = A  + (size_t)m0 * KD;
    const bf16_t* Bg = Wb + (size_t)n0 * KD;
    f32x4 acc[4][4] = {};
    const int lm = lane & 15;
    const int ks = (lane >> 4) << 3;

    for (int k0 = 0; k0 < KD; k0 += 32) {
        stage128x32(Ag + k0, As, tid);
        stage128x32(Bg + k0, Bs, tid);
        __syncthreads();
        bf16x8 af[4], bfr[4];
        #pragma unroll
        for (int i = 0; i < 4; ++i)
            af[i] = *(bf16x8*)&As[((wy << 6) + (i << 4) + lm) * 32 + ks];
        #pragma unroll
        for (int j = 0; j < 4; ++j)
            bfr[j] = *(bf16x8*)&Bs[((wx << 6) + (j << 4) + lm) * 32 + ks];
        #pragma unroll
        for (int i = 0; i < 4; ++i)
            #pragma unroll
            for (int j = 0; j < 4; ++j)
                acc[i][j] = __builtin_amdgcn_mfma_f32_16x16x32_bf16(
                                af[i], bfr[j], acc[i][j], 0, 0, 0);
        __syncthreads();
    }

    const int row4 = (lane >> 4) << 2;
    #pragma unroll
    for (int i = 0; i < 4; ++i) {
        #pragma unroll
        for (int r = 0; r < 4; ++r) {
            int m = m0 + (wy << 6) + (i << 4) + row4 + r;
            #pragma unroll
            for (int j = 0; j < 4; ++j) {
                int n = n0 + (wx << 6) + (j << 4) + lm;
                out[(size_t)m * DD + n] = acc[i][j][r] + bias[n] + res[(size_t)m * DD + n];
            }
        }
    }
}

// ---------------- in-proj GEMM, transposed output: u_ch[h][token] bf16 --------
// u_ch[m=h][n=token] = sum_k in_W[h,k] x[token,k] + in_b[h]
__global__ __launch_bounds__(256)
void gemm_inT_kernel(const bf16_t* __restrict__ Wb, const bf16_t* __restrict__ X,
                     const float* __restrict__ bias, bf16_t* __restrict__ u_ch)
{
    __shared__ bf16_t As[128 * 32];
    __shared__ bf16_t Bs[128 * 32];
    const int tid = threadIdx.x;
    const int lane = tid & 63, w = tid >> 6;
    const int wy = w >> 1, wx = w & 1;
    const int m0 = blockIdx.y << 7, n0 = blockIdx.x << 7;   // m0: h, n0: token
    const bf16_t* Ag = Wb + (size_t)m0 * KD;
    const bf16_t* Bg = X  + (size_t)n0 * KD;
    f32x4 acc[4][4] = {};
    const int lm = lane & 15;
    const int ks = (lane >> 4) << 3;

    for (int k0 = 0; k0 < KD; k0 += 32) {
        stage128x32(Ag + k0, As, tid);
        stage128x32(Bg + k0, Bs, tid);
        __syncthreads();
        bf16x8 af[4], bfr[4];
        #pragma unroll
        for (int i = 0; i < 4; ++i)
            af[i] = *(bf16x8*)&As[((wy << 6) + (i << 4) + lm) * 32 + ks];
        #pragma unroll
        for (int j = 0; j < 4; ++j)
            bfr[j] = *(bf16x8*)&Bs[((wx << 6) + (j << 4) + lm) * 32 + ks];
        #pragma unroll
        for (int i = 0; i < 4; ++i)
            #pragma unroll
            for (int j = 0; j < 4; ++j)
                acc[i][j] = __builtin_amdgcn_mfma_f32_16x16x32_bf16(
                                af[i], bfr[j], acc[i][j], 0, 0, 0);
        __syncthreads();
    }

    const int row4 = (lane >> 4) << 2;
    #pragma unroll
    for (int i = 0; i < 4; ++i) {
        #pragma unroll
        for (int r = 0; r < 4; ++r) {
            int m = m0 + (wy << 6) + (i << 4) + row4 + r;       // h
            float bm = bias[m];
            #pragma unroll
            for (int j = 0; j < 4; ++j) {
                int n = n0 + (wx << 6) + (j << 4) + lm;         // token
                u_ch[(size_t)m * (BB * LL) + n] = (bf16_t)(acc[i][j][r] + bm);
            }
        }
    }
}

// ---------------- fused GLU GEMM: za=y@Wa^T+ba, zg=y@Wg^T+bg ; v=za*sig(zg) ---
__global__ __launch_bounds__(256)
void gemm_glu16_kernel(const bf16_t* __restrict__ A, const bf16_t* __restrict__ Wb,
                       const float* __restrict__ bias, bf16_t* __restrict__ vout)
{
    __shared__ bf16_t As[128 * 32];
    __shared__ bf16_t Ba[128 * 32];
    __shared__ bf16_t Bg[128 * 32];
    const int tid = threadIdx.x;
    const int lane = tid & 63, w = tid >> 6;
    const int wy = w >> 1, wx = w & 1;
    const int m0 = blockIdx.y << 7, n0 = blockIdx.x << 7;
    const bf16_t* Ag  = A  + (size_t)m0 * KD;
    const bf16_t* Bga = Wb + (size_t)n0 * KD;
    const bf16_t* Bgg = Wb + ((size_t)n0 + DD) * KD;
    f32x4 aca[4][4] = {}, acg[4][4] = {};
    const int lm = lane & 15;
    const int ks = (lane >> 4) << 3;

    for (int k0 = 0; k0 < KD; k0 += 32) {
        stage128x32(Ag  + k0, As, tid);
        stage128x32(Bga + k0, Ba, tid);
        stage128x32(Bgg + k0, Bg, tid);
        __syncthreads();
        bf16x8 af[4];
        #pragma unroll
        for (int i = 0; i < 4; ++i)
            af[i] = *(bf16x8*)&As[((wy << 6) + (i << 4) + lm) * 32 + ks];
        #pragma unroll
        for (int j = 0; j < 4; ++j) {
            bf16x8 ba = *(bf16x8*)&Ba[((wx << 6) + (j << 4) + lm) * 32 + ks];
            bf16x8 bg = *(bf16x8*)&Bg[((wx << 6) + (j << 4) + lm) * 32 + ks];
            #pragma unroll
            for (int i = 0; i < 4; ++i) {
                aca[i][j] = __builtin_amdgcn_mfma_f32_16x16x32_bf16(af[i], ba, aca[i][j], 0, 0, 0);
                acg[i][j] = __builtin_amdgcn_mfma_f32_16x16x32_bf16(af[i], bg, acg[i][j], 0, 0, 0);
            }
        }
        __syncthreads();
    }

    const int row4 = (lane >> 4) << 2;
    #pragma unroll
    for (int i = 0; i < 4; ++i) {
        #pragma unroll
        for (int r = 0; r < 4; ++r) {
            int m = m0 + (wy << 6) + (i << 4) + row4 + r;
            #pragma unroll
            for (int j = 0; j < 4; ++j) {
                int n = n0 + (wx << 6) + (j << 4) + lm;
                float za = aca[i][j][r] + bias[n];
                float zg = acg[i][j][r] + bias[DD + n];
                vout[(size_t)m * DD + n] = (bf16_t)(za / (1.f + expf(-zg)));
            }
        }
    }
}

// ---------------- gen V: V[h][comp][l] = Re/Im(w_h,n^(63-l)), bf16 ------------
__global__ __launch_bounds__(64)
void genV_kernel(const float* __restrict__ log_dt, const float* __restrict__ lar,
                 const float* __restrict__ aim, bf16_t* __restrict__ V)
{
    const int tid = threadIdx.x;
    const int h = blockIdx.x * 2 + (tid >> 5);
    const int n = tid & 31;
    const float dt = expf(log_dt[h]);
    const float ardt = -expf(lar[h * NM + n]) * dt;
    const float aidt = aim[h * NM + n] * dt;
    float sn, cs;
    sincosf(aidt, &sn, &cs);
    float er = expf(ardt);
    float wr = er * cs, wi = er * sn;
    float inv = 1.f / fmaf(wr, wr, wi * wi);
    float vr = wr * inv, vi = -wi * inv;          // w^-1
    sincosf(63.f * aidt, &sn, &cs);
    er = expf(63.f * ardt);
    float pr = er * cs, pi = er * sn;             // w^63
    bf16_t* rowr = V + ((size_t)h * 64 + 2 * n) * 64;
    bf16_t* rowi = rowr + 64;
    #pragma unroll
    for (int c8 = 0; c8 < 8; ++c8) {
        bf16x8 rr, ri;
        #pragma unroll
        for (int e = 0; e < 8; ++e) {
            rr[e] = (bf16_t)pr; ri[e] = (bf16_t)pi;
            float t = fmaf(pr, vr, -pi * vi);
            pi = fmaf(pr, vi, pi * vr);
            pr = t;
        }
        *(bf16x8*)(rowr + c8 * 8) = rr;
        *(bf16x8*)(rowi + c8 * 8) = ri;
    }
}

// ---------------- gen TP: TP[h][i][0:64]=Toeplitz K[i-l] (+skip), [64:128]=P --
__global__ __launch_bounds__(64)
void genTP_kernel(const float* __restrict__ log_dt, const float* __restrict__ lar,
                  const float* __restrict__ aim, const float* __restrict__ Cp,
                  const float* __restrict__ dskip, bf16_t* __restrict__ TP)
{
    __shared__ float ardt_s[NM], aidt_s[NM], cr_s[NM], ci_s[NM], K_s[CL];
    const int h = blockIdx.x;
    const int tid = threadIdx.x;
    const float dt = expf(log_dt[h]);
    if (tid < NM) {
        int n = tid;
        float ar = -expf(lar[h * NM + n]);
        float ai = aim[h * NM + n];
        float sn, cs;
        sincosf(ai * dt, &sn, &cs);
        float er = expf(ar * dt);
        float wrr = er * cs, wii = er * sn;
        float Crr = Cp[(h * NM + n) * 2 + 0];
        float Cii = Cp[(h * NM + n) * 2 + 1];
        float nr = fmaf(Crr, wrr - 1.f, -Cii * wii);
        float ni = fmaf(Crr, wii, Cii * (wrr - 1.f));
        float inv = 2.f / fmaf(ar, ar, ai * ai);
        cr_s[n] = fmaf(nr, ar, ni * ai) * inv;
        ci_s[n] = fmaf(ni, ar, -nr * ai) * inv;
        ardt_s[n] = ar * dt;
        aidt_s[n] = ai * dt;
    }
    __syncthreads();
    {   // K[d] = sum_n cr*Re(w^d) - ci*Im(w^d);  K[0] += D_skip
        float d = (float)tid;
        float kv = (tid == 0) ? dskip[h] : 0.f;
        #pragma unroll 8
        for (int n = 0; n < NM; ++n) {
            float sn, cs;
            sincosf(aidt_s[n] * d, &sn, &cs);
            float e = expf(ardt_s[n] * d);
            kv = fmaf(cr_s[n], e * cs, kv);
            kv = fmaf(-ci_s[n], e * sn, kv);
        }
        K_s[tid] = kv;
    }
    __syncthreads();
    const int i = tid;
    bf16_t* row = TP + ((size_t)h * CL + i) * 128;
    #pragma unroll
    for (int c8 = 0; c8 < 8; ++c8) {
        bf16x8 v;
        #pragma unroll
        for (int e = 0; e < 8; ++e) {
            int l = c8 * 8 + e;
            v[e] = (l <= i) ? (bf16_t)K_s[i - l] : (bf16_t)0.f;
        }
        *(bf16x8*)(row + c8 * 8) = v;
    }
    const float fi = (float)(i + 1);
    #pragma unroll
    for (int c8 = 0; c8 < 8; ++c8) {
        bf16x8 v;
        #pragma unroll
        for (int q = 0; q < 4; ++q) {
            int n = c8 * 4 + q;
            float sn, cs;
            sincosf(aidt_s[n] * fi, &sn, &cs);
            float e = expf(ardt_s[n] * fi);
            float Wr = e * cs, Wi = e * sn;
            v[2 * q]     = (bf16_t)(fmaf(cr_s[n], Wr, -ci_s[n] * Wi));
            v[2 * q + 1] = (bf16_t)(-fmaf(cr_s[n], Wi, ci_s[n] * Wr));
        }
        *(bf16x8*)(row + 64 + c8 * 8) = v;
    }
}

// ---------------- G1: per-channel S_bc[batch][comp] = U[batch][l] @ V[comp][l]
__global__ __launch_bounds__(256)
void g1_kernel(const bf16_t* __restrict__ u_ch, const bf16_t* __restrict__ V,
               float* __restrict__ Sbc)
{
    const int h = blockIdx.x;
    const int tid = threadIdx.x;
    const int lane = tid & 63, w = tid >> 6;
    const int lm = lane & 15, ks = (lane >> 4) << 3;
    const bf16_t* U  = u_ch + (size_t)h * 8192;   // [128 batch][64 l]
    const bf16_t* Vh = V    + (size_t)h * 4096;   // [64 comp][64 l]
    f32x4 acc[2][4] = {};
    #pragma unroll
    for (int kk = 0; kk < 2; ++kk) {
        int k0 = kk * 32;
        bf16x8 af[2], bfr[4];
        #pragma unroll
        for (int im = 0; im < 2; ++im)
            af[im] = *(const bf16x8*)(U + (((w << 1) + im) * 16 + lm) * 64 + k0 + ks);
        #pragma unroll
        for (int jn = 0; jn < 4; ++jn)
            bfr[jn] = *(const bf16x8*)(Vh + (jn * 16 + lm) * 64 + k0 + ks);
        #pragma unroll
        for (int im = 0; im < 2; ++im)
            #pragma unroll
            for (int jn = 0; jn < 4; ++jn)
                acc[im][jn] = __builtin_amdgcn_mfma_f32_16x16x32_bf16(
                                  af[im], bfr[jn], acc[im][jn], 0, 0, 0);
    }
    float* out = Sbc + (size_t)h * 8192;          // [128 batch][64 comp]
    const int r4 = (lane >> 4) << 2;
    #pragma unroll
    for (int im = 0; im < 2; ++im)
        #pragma unroll
        for (int jn = 0; jn < 4; ++jn)
            #pragma unroll
            for (int r = 0; r < 4; ++r) {
                int batch = ((w << 1) + im) * 16 + r4 + r;
                int comp  = jn * 16 + lm;
                out[batch * 64 + comp] = acc[im][jn][r];
            }
}

// ---------------- passB: carry scan over chunks (per h, b; 32 mode-lanes) -----
__global__ __launch_bounds__(256)
void passB_kernel(const float* __restrict__ Sbc, const float* __restrict__ log_dt,
                  const float* __restrict__ lar, const float* __restrict__ aim,
                  bf16_t* __restrict__ Sc)
{
    const int tid = threadIdx.x;
    const int gid = blockIdx.x * 8 + (tid >> 5);  // 8192 groups
    const int h = gid >> 3, b = gid & 7;
    const int n = tid & 31;
    const float dt = expf(log_dt[h]);
    const float ardt = -expf(lar[h * NM + n]) * dt;
    const float aidt = aim[h * NM + n] * dt;
    float sn, cs;
    sincosf(64.f * aidt, &sn, &cs);
    float er = expf(64.f * ardt);
    const float gr = er * cs, gi = er * sn;       // w^CL
    float sr = 0.f, si = 0.f;
    for (int c = 0; c < NCH; ++c) {
        size_t base = (size_t)h * 8192 + (b * 16 + c) * 64 + 2 * n;
        float2 lv = *(const float2*)(Sbc + base);
        Sc[base]     = (bf16_t)sr;                // carry-in state for chunk c
        Sc[base + 1] = (bf16_t)si;
        float t = fmaf(gr, sr, fmaf(-gi, si, lv.x));
        si = fmaf(gr, si, fmaf(gi, sr, lv.y));
        sr = t;
    }
}

// ---------------- G3: per-channel Y[batch][i] = [U|Sc] @ TP^T, gelu, bf16 -----
__global__ __launch_bounds__(256)
void g3_kernel(const bf16_t* __restrict__ u_ch, const bf16_t* __restrict__ Sc,
               const bf16_t* __restrict__ TP, bf16_t* __restrict__ y_bi)
{
    const int h = blockIdx.x;
    const int tid = threadIdx.x;
    const int lane = tid & 63, w = tid >> 6;
    const int lm = lane & 15, ks = (lane >> 4) << 3;
    const bf16_t* U   = u_ch + (size_t)h * 8192;  // [128 batch][64 l]
    const bf16_t* Sch = Sc   + (size_t)h * 8192;  // [128 batch][64 comp]
    const bf16_t* TPh = TP   + (size_t)h * 8192;  // [64 i][128 k]
    f32x4 acc[2][4] = {};
    #pragma unroll
    for (int kk = 0; kk < 4; ++kk) {
        const bf16_t* Ab = (kk < 2) ? (U + kk * 32) : (Sch + (kk - 2) * 32);
        bf16x8 af[2], bfr[4];
        #pragma unroll
        for (int im = 0; im < 2; ++im)
            af[im] = *(const bf16x8*)(Ab + (((w << 1) + im) * 16 + lm) * 64 + ks);
        #pragma unroll
        for (int jn = 0; jn < 4; ++jn)
            bfr[jn] = *(const bf16x8*)(TPh + (jn * 16 + lm) * 128 + kk * 32 + ks);
        #pragma unroll
        for (int im = 0; im < 2; ++im)
            #pragma unroll
            for (int jn = 0; jn < 4; ++jn)
                acc[im][jn] = __builtin_amdgcn_mfma_f32_16x16x32_bf16(
                                  af[im], bfr[jn], acc[im][jn], 0, 0, 0);
    }
    bf16_t* out = y_bi + (size_t)h * 8192;        // [128 batch][64 i]
    const int r4 = (lane >> 4) << 2;
    #pragma unroll
    for (int im = 0; im < 2; ++im)
        #pragma unroll
        for (int jn = 0; jn < 4; ++jn)
            #pragma unroll
            for (int r = 0; r < 4; ++r) {
                int batch = ((w << 1) + im) * 16 + r4 + r;
                int i = jn * 16 + lm;
                out[batch * 64 + i] = (bf16_t)gelu_f(acc[im][jn][r]);
            }
}

// ---------------- 64x64 bf16 tile transpose: dst[c][r] = src[r][c] ------------
__global__ __launch_bounds__(256)
void transpose_kernel(const bf16_t* __restrict__ src, bf16_t* __restrict__ dst,
                      int src_rows, int src_cols)
{
    __shared__ unsigned short tile[64][68];
    const int tid = threadIdx.x;
    const int c0 = blockIdx.x << 6, r0 = blockIdx.y << 6;
    const int r = tid >> 4, c4 = (tid & 15) << 2;
    #pragma unroll
    for (int p = 0; p < 4; ++p) {
        int rr = p * 16 + r;
        ushort4 v = *(const ushort4*)((const unsigned short*)src +
                                      (size_t)(r0 + rr) * src_cols + c0 + c4);
        *(ushort4*)&tile[rr][c4] = v;
    }
    __syncthreads();
    #pragma unroll
    for (int p = 0; p < 4; ++p) {
        int rr = p * 16 + r;                      // dst-row-local (src col)
        ushort4 v;
        v.x = tile[c4 + 0][rr];
        v.y = tile[c4 + 1][rr];
        v.z = tile[c4 + 2][rr];
        v.w = tile[c4 + 3][rr];
        *(ushort4*)((unsigned short*)dst + (size_t)(c0 + rr) * src_rows + r0 + c4) = v;
    }
}

extern "C" void kernel_launch(void* const* d_in, const int* in_sizes, int n_in,
                              void* d_out, int out_size, void* d_ws, size_t ws_size,
                              hipStream_t stream)
{
    (void)in_sizes; (void)n_in; (void)out_size; (void)ws_size;
    const float* x      = (const float*)d_in[0];
    const float* in_W   = (const float*)d_in[1];
    const float* in_b   = (const float*)d_in[2];
    const float* log_dt = (const float*)d_in[3];
    const float* Cp     = (const float*)d_in[4];
    const float* lar    = (const float*)d_in[5];
    const float* aim    = (const float*)d_in[6];
    const float* dsk    = (const float*)d_in[7];
    const float* gluW   = (const float*)d_in[8];
    const float* glub   = (const float*)d_in[9];
    const float* outW   = (const float*)d_in[10];
    const float* outb   = (const float*)d_in[11];

    const int NTOK = BB * LL;                     // 8192 tokens
    // ws layout (58.7 MiB peak, same as passing round 3):
    //  [0,16M):  xb -> (after gemm_inT) TP -> (after G3) y_tok
    //  [16,32M): V [16,24M) -> (after G1) S_carry -> (after G3) vb
    //  [32,48M): u_ch (bf16, channel-major)
    //  [48M..):  wbin 2M | wbglu 4M | wbout 2M
    // d_out: S_bc fp32 (32M) -> y_bi bf16 (16M) -> final output
    char* ws = (char*)d_ws;
    bf16_t* xb    = (bf16_t*)(ws);
    bf16_t* TP    = (bf16_t*)(ws);
    bf16_t* y_tok = (bf16_t*)(ws);
    bf16_t* V     = (bf16_t*)(ws + 16777216);
    bf16_t* Sc    = (bf16_t*)(ws + 16777216);
    bf16_t* vb    = (bf16_t*)(ws + 16777216);
    bf16_t* u_ch  = (bf16_t*)(ws + 33554432);
    bf16_t* wbin  = (bf16_t*)(ws + 50331648);
    bf16_t* wbglu = (bf16_t*)(ws + 52428800);
    bf16_t* wbout = (bf16_t*)(ws + 56623104);
    float*  Sbc   = (float*)d_out;
    bf16_t* y_bi  = (bf16_t*)d_out;

    f2b_kernel<<<dim3(NTOK * DD / 1024), dim3(256), 0, stream>>>(x,    xb,    NTOK * DD);
    f2b_kernel<<<dim3(DD * DD / 1024),   dim3(256), 0, stream>>>(in_W, wbin,  DD * DD);
    f2b_kernel<<<dim3(2 * DD * DD / 1024), dim3(256), 0, stream>>>(gluW, wbglu, 2 * DD * DD);
    f2b_kernel<<<dim3(DD * DD / 1024),   dim3(256), 0, stream>>>(outW, wbout, DD * DD);

    // in-proj, channel-major output
    gemm_inT_kernel<<<dim3(NTOK / 128, DD / 128), dim3(256), 0, stream>>>(wbin, xb, in_b, u_ch);

    // SSM as per-channel MFMA GEMMs
    genV_kernel <<<dim3(DD / 2), dim3(64), 0, stream>>>(log_dt, lar, aim, V);
    genTP_kernel<<<dim3(DD),     dim3(64), 0, stream>>>(log_dt, lar, aim, Cp, dsk, TP);
    g1_kernel   <<<dim3(DD), dim3(256), 0, stream>>>(u_ch, V, Sbc);
    passB_kernel<<<dim3(DD * BB / 8), dim3(256), 0, stream>>>(Sbc, log_dt, lar, aim, Sc);
    g3_kernel   <<<dim3(DD), dim3(256), 0, stream>>>(u_ch, Sc, TP, y_bi);

    // back to token-major, then GLU + out-proj
    transpose_kernel<<<dim3(NTOK / 64, DD / 64), dim3(256), 0, stream>>>(y_bi, y_tok, DD, NTOK);
    gemm_glu16_kernel<<<dim3(DD / 128, NTOK / 128), dim3(256), 0, stream>>>(y_tok, wbglu, glub, vb);
    gemm_out_kernel  <<<dim3(DD / 128, NTOK / 128), dim3(256), 0, stream>>>(vb, wbout, outb, x, (float*)d_out);
}

// Round 7
// 309.640 us; speedup vs baseline: 3.6143x; 1.0953x over previous
//
#include <hip/hip_runtime.h>
#include <math.h>

#define BB 8
#define LL 1024
#define DD 1024
#define KD 1024   // GEMM K depth (token-space GEMMs)
#define NM 32     // complex modes per channel
#define NCH 16    // chunks over L
#define CL 64     // chunk length (NCH*CL == LL)
#define NTOK (BB * LL)

typedef __bf16 bf16_t;
typedef __bf16 bf16x8 __attribute__((ext_vector_type(8)));
typedef __bf16 bf16x4 __attribute__((ext_vector_type(4)));
typedef float  f32x4  __attribute__((ext_vector_type(4)));

__device__ __forceinline__ float gelu_f(float z)
{
    float t = fmaf(0.044715f * z * z, z, z);
    return z / (1.f + expf(-1.5957691216f * t));
}

// ---------------- fused fp32 -> bf16 converts (x, in_W, gluW, outW) -----------
__global__ __launch_bounds__(256)
void f2b_all_kernel(const float* __restrict__ x,    bf16_t* __restrict__ xb,
                    const float* __restrict__ w0,   bf16_t* __restrict__ d0,
                    const float* __restrict__ w1,   bf16_t* __restrict__ d1,
                    const float* __restrict__ w2,   bf16_t* __restrict__ d2)
{
    int b = blockIdx.x;
    const float* s; bf16_t* d; int base;
    if (b < 8192)       { s = x;  d = xb; base = b; }
    else if (b < 9216)  { s = w0; d = d0; base = b - 8192; }
    else if (b < 11264) { s = w1; d = d1; base = b - 9216; }
    else                { s = w2; d = d2; base = b - 11264; }
    int i = (base * 256 + threadIdx.x) * 4;
    float4 f = *(const float4*)(s + i);
    bf16x4 o = { (bf16_t)f.x, (bf16_t)f.y, (bf16_t)f.z, (bf16_t)f.w };
    *(bf16x4*)(d + i) = o;
}

// ---------------- global->LDS staging: 128 rows x 32 bf16 (verified pattern) --
// Identical byte pattern to rounds 2-5: 4-lane clusters read 64 contiguous B,
// LDS row-major [128][32], dst = wave-uniform base + lane*16.
__device__ __forceinline__ void stage128x32(const bf16_t* __restrict__ g,
                                            bf16_t* lds, int tid)
{
    #pragma unroll
    for (int q = 0; q < 2; ++q) {
        const bf16_t* src = g + (size_t)(q * 64 + (tid >> 2)) * KD + (tid & 3) * 8;
        bf16_t* dst = lds + q * 2048 + tid * 8;
        __builtin_amdgcn_global_load_lds(
            (const __attribute__((address_space(1))) void*)src,
            (__attribute__((address_space(3))) void*)dst, 16, 0, 0);
    }
}

// ---------------- BK=64 (2x BK=32 panels) MFMA GEMM + epilogue ----------------
// MODE 0: bf16 out = acc + bias[m]            (in-proj, channel-major out)
// MODE 1: bf16 out = acc + bias[n]            (GLU z)
// MODE 2: f32  out = acc + bias[n] + res[m,n] (out-proj + residual)
template<int MODE>
__global__ __launch_bounds__(256)
void gemm_bk64_kernel(const bf16_t* __restrict__ A, const bf16_t* __restrict__ B,
                      const float* __restrict__ bias, const float* __restrict__ res,
                      void* __restrict__ outp, int ldo)
{
    __shared__ bf16_t As[2][128 * 32];
    __shared__ bf16_t Bs[2][128 * 32];
    const int tid = threadIdx.x;
    const int lane = tid & 63, w = tid >> 6;
    const int wy = w >> 1, wx = w & 1;
    const int m0 = blockIdx.y << 7, n0 = blockIdx.x << 7;
    const bf16_t* Ag = A + (size_t)m0 * KD;
    const bf16_t* Bg = B + (size_t)n0 * KD;
    f32x4 acc[4][4] = {};
    const int lm = lane & 15;
    const int ks = (lane >> 4) << 3;

    for (int k0 = 0; k0 < KD; k0 += 64) {
        stage128x32(Ag + k0,      As[0], tid);
        stage128x32(Bg + k0,      Bs[0], tid);
        stage128x32(Ag + k0 + 32, As[1], tid);
        stage128x32(Bg + k0 + 32, Bs[1], tid);
        __syncthreads();
        #pragma unroll
        for (int p = 0; p < 2; ++p) {
            bf16x8 af[4], bfr[4];
            #pragma unroll
            for (int i = 0; i < 4; ++i)
                af[i] = *(bf16x8*)&As[p][((wy << 6) + (i << 4) + lm) * 32 + ks];
            #pragma unroll
            for (int j = 0; j < 4; ++j)
                bfr[j] = *(bf16x8*)&Bs[p][((wx << 6) + (j << 4) + lm) * 32 + ks];
            #pragma unroll
            for (int i = 0; i < 4; ++i)
                #pragma unroll
                for (int j = 0; j < 4; ++j)
                    acc[i][j] = __builtin_amdgcn_mfma_f32_16x16x32_bf16(
                                    af[i], bfr[j], acc[i][j], 0, 0, 0);
        }
        __syncthreads();
    }

    const int row4 = (lane >> 4) << 2;
    #pragma unroll
    for (int i = 0; i < 4; ++i) {
        #pragma unroll
        for (int r = 0; r < 4; ++r) {
            int m = m0 + (wy << 6) + (i << 4) + row4 + r;
            #pragma unroll
            for (int j = 0; j < 4; ++j) {
                int n = n0 + (wx << 6) + (j << 4) + lm;
                float v = acc[i][j][r];
                if (MODE == 0) {
                    ((bf16_t*)outp)[(size_t)m * ldo + n] = (bf16_t)(v + bias[m]);
                } else if (MODE == 1) {
                    ((bf16_t*)outp)[(size_t)m * ldo + n] = (bf16_t)(v + bias[n]);
                } else {
                    ((float*)outp)[(size_t)m * ldo + n] =
                        v + bias[n] + res[(size_t)m * ldo + n];
                }
            }
        }
    }
}

// ---------------- GLU combine: v = za * sigmoid(zg), bf16 ---------------------
__global__ __launch_bounds__(256)
void glu_combine_kernel(const bf16_t* __restrict__ z, bf16_t* __restrict__ v)
{
    int i = blockIdx.x * 256 + threadIdx.x;       // one thread = 8 elements
    int m = i >> 7, n8 = (i & 127) << 3;
    const bf16_t* zp = z + (size_t)m * 2048 + n8;
    bf16x8 za = *(const bf16x8*)zp;
    bf16x8 zg = *(const bf16x8*)(zp + 1024);
    bf16x8 o;
    #pragma unroll
    for (int e = 0; e < 8; ++e) {
        float a = (float)za[e], gg = (float)zg[e];
        o[e] = (bf16_t)(a / (1.f + expf(-gg)));
    }
    *(bf16x8*)(v + (size_t)m * 1024 + n8) = o;
}

// ---------------- gen V: V[h][comp][l] = Re/Im(w_h,n^(63-l)), bf16 ------------
__global__ __launch_bounds__(64)
void genV_kernel(const float* __restrict__ log_dt, const float* __restrict__ lar,
                 const float* __restrict__ aim, bf16_t* __restrict__ V)
{
    const int tid = threadIdx.x;
    const int h = blockIdx.x * 2 + (tid >> 5);
    const int n = tid & 31;
    const float dt = expf(log_dt[h]);
    const float ardt = -expf(lar[h * NM + n]) * dt;
    const float aidt = aim[h * NM + n] * dt;
    float sn, cs;
    sincosf(aidt, &sn, &cs);
    float er = expf(ardt);
    float wr = er * cs, wi = er * sn;
    float inv = 1.f / fmaf(wr, wr, wi * wi);
    float vr = wr * inv, vi = -wi * inv;          // w^-1
    sincosf(63.f * aidt, &sn, &cs);
    er = expf(63.f * ardt);
    float pr = er * cs, pi = er * sn;             // w^63
    bf16_t* rowr = V + ((size_t)h * 64 + 2 * n) * 64;
    bf16_t* rowi = rowr + 64;
    #pragma unroll
    for (int c8 = 0; c8 < 8; ++c8) {
        bf16x8 rr, ri;
        #pragma unroll
        for (int e = 0; e < 8; ++e) {
            rr[e] = (bf16_t)pr; ri[e] = (bf16_t)pi;
            float t = fmaf(pr, vr, -pi * vi);
            pi = fmaf(pr, vi, pi * vr);
            pr = t;
        }
        *(bf16x8*)(rowr + c8 * 8) = rr;
        *(bf16x8*)(rowi + c8 * 8) = ri;
    }
}

// ---------------- gen TP: TP[h][i][0:64]=Toeplitz K[i-l] (+skip), [64:128]=P --
__global__ __launch_bounds__(64)
void genTP_kernel(const float* __restrict__ log_dt, const float* __restrict__ lar,
                  const float* __restrict__ aim, const float* __restrict__ Cp,
                  const float* __restrict__ dskip, bf16_t* __restrict__ TP)
{
    __shared__ float ardt_s[NM], aidt_s[NM], cr_s[NM], ci_s[NM], K_s[CL];
    const int h = blockIdx.x;
    const int tid = threadIdx.x;
    const float dt = expf(log_dt[h]);
    if (tid < NM) {
        int n = tid;
        float ar = -expf(lar[h * NM + n]);
        float ai = aim[h * NM + n];
        float sn, cs;
        sincosf(ai * dt, &sn, &cs);
        float er = expf(ar * dt);
        float wrr = er * cs, wii = er * sn;
        float Crr = Cp[(h * NM + n) * 2 + 0];
        float Cii = Cp[(h * NM + n) * 2 + 1];
        float nr = fmaf(Crr, wrr - 1.f, -Cii * wii);
        float ni = fmaf(Crr, wii, Cii * (wrr - 1.f));
        float inv = 2.f / fmaf(ar, ar, ai * ai);
        cr_s[n] = fmaf(nr, ar, ni * ai) * inv;
        ci_s[n] = fmaf(ni, ar, -nr * ai) * inv;
        ardt_s[n] = ar * dt;
        aidt_s[n] = ai * dt;
    }
    __syncthreads();
    {   // K[d] = sum_n cr*Re(w^d) - ci*Im(w^d);  K[0] += D_skip
        float d = (float)tid;
        float kv = (tid == 0) ? dskip[h] : 0.f;
        #pragma unroll 8
        for (int n = 0; n < NM; ++n) {
            float sn, cs;
            sincosf(aidt_s[n] * d, &sn, &cs);
            float e = expf(ardt_s[n] * d);
            kv = fmaf(cr_s[n], e * cs, kv);
            kv = fmaf(-ci_s[n], e * sn, kv);
        }
        K_s[tid] = kv;
    }
    __syncthreads();
    const int i = tid;
    bf16_t* row = TP + ((size_t)h * CL + i) * 128;
    #pragma unroll
    for (int c8 = 0; c8 < 8; ++c8) {
        bf16x8 v;
        #pragma unroll
        for (int e = 0; e < 8; ++e) {
            int l = c8 * 8 + e;
            v[e] = (l <= i) ? (bf16_t)K_s[i - l] : (bf16_t)0.f;
        }
        *(bf16x8*)(row + c8 * 8) = v;
    }
    const float fi = (float)(i + 1);
    #pragma unroll
    for (int c8 = 0; c8 < 8; ++c8) {
        bf16x8 v;
        #pragma unroll
        for (int q = 0; q < 4; ++q) {
            int n = c8 * 4 + q;
            float sn, cs;
            sincosf(aidt_s[n] * fi, &sn, &cs);
            float e = expf(ardt_s[n] * fi);
            float Wr = e * cs, Wi = e * sn;
            v[2 * q]     = (bf16_t)(fmaf(cr_s[n], Wr, -ci_s[n] * Wi));
            v[2 * q + 1] = (bf16_t)(-fmaf(cr_s[n], Wi, ci_s[n] * Wr));
        }
        *(bf16x8*)(row + 64 + c8 * 8) = v;
    }
}

// ---------------- G1: per-channel S_bc[batch][comp] = U[batch][l] @ V[comp][l]
__global__ __launch_bounds__(256)
void g1_kernel(const bf16_t* __restrict__ u_ch, const bf16_t* __restrict__ V,
               float* __restrict__ Sbc)
{
    const int h = blockIdx.x;
    const int tid = threadIdx.x;
    const int lane = tid & 63, w = tid >> 6;
    const int lm = lane & 15, ks = (lane >> 4) << 3;
    const bf16_t* U  = u_ch + (size_t)h * 8192;   // [128 batch][64 l]
    const bf16_t* Vh = V    + (size_t)h * 4096;   // [64 comp][64 l]
    f32x4 acc[2][4] = {};
    #pragma unroll
    for (int kk = 0; kk < 2; ++kk) {
        int k0 = kk * 32;
        bf16x8 af[2], bfr[4];
        #pragma unroll
        for (int im = 0; im < 2; ++im)
            af[im] = *(const bf16x8*)(U + (((w << 1) + im) * 16 + lm) * 64 + k0 + ks);
        #pragma unroll
        for (int jn = 0; jn < 4; ++jn)
            bfr[jn] = *(const bf16x8*)(Vh + (jn * 16 + lm) * 64 + k0 + ks);
        #pragma unroll
        for (int im = 0; im < 2; ++im)
            #pragma unroll
            for (int jn = 0; jn < 4; ++jn)
                acc[im][jn] = __builtin_amdgcn_mfma_f32_16x16x32_bf16(
                                  af[im], bfr[jn], acc[im][jn], 0, 0, 0);
    }
    float* out = Sbc + (size_t)h * 8192;          // [128 batch][64 comp]
    const int r4 = (lane >> 4) << 2;
    #pragma unroll
    for (int im = 0; im < 2; ++im)
        #pragma unroll
        for (int jn = 0; jn < 4; ++jn)
            #pragma unroll
            for (int r = 0; r < 4; ++r) {
                int batch = ((w << 1) + im) * 16 + r4 + r;
                int comp  = jn * 16 + lm;
                out[batch * 64 + comp] = acc[im][jn][r];
            }
}

// ---------------- passB: carry scan over chunks (per h, b; 32 mode-lanes) -----
__global__ __launch_bounds__(256)
void passB_kernel(const float* __restrict__ Sbc, const float* __restrict__ log_dt,
                  const float* __restrict__ lar, const float* __restrict__ aim,
                  bf16_t* __restrict__ Sc)
{
    const int tid = threadIdx.x;
    const int gid = blockIdx.x * 8 + (tid >> 5);  // 8192 groups
    const int h = gid >> 3, b = gid & 7;
    const int n = tid & 31;
    const float dt = expf(log_dt[h]);
    const float ardt = -expf(lar[h * NM + n]) * dt;
    const float aidt = aim[h * NM + n] * dt;
    float sn, cs;
    sincosf(64.f * aidt, &sn, &cs);
    float er = expf(64.f * ardt);
    const float gr = er * cs, gi = er * sn;       // w^CL
    float sr = 0.f, si = 0.f;
    for (int c = 0; c < NCH; ++c) {
        size_t base = (size_t)h * 8192 + (b * 16 + c) * 64 + 2 * n;
        float2 lv = *(const float2*)(Sbc + base);
        Sc[base]     = (bf16_t)sr;                // carry-in state for chunk c
        Sc[base + 1] = (bf16_t)si;
        float t = fmaf(gr, sr, fmaf(-gi, si, lv.x));
        si = fmaf(gr, si, fmaf(gi, sr, lv.y));
        sr = t;
    }
}

// ---------------- G3: per-channel Y[batch][i] = [U|Sc] @ TP^T, gelu, bf16 -----
__global__ __launch_bounds__(256)
void g3_kernel(const bf16_t* __restrict__ u_ch, const bf16_t* __restrict__ Sc,
               const bf16_t* __restrict__ TP, bf16_t* __restrict__ y_bi)
{
    const int h = blockIdx.x;
    const int tid = threadIdx.x;
    const int lane = tid & 63, w = tid >> 6;
    const int lm = lane & 15, ks = (lane >> 4) << 3;
    const bf16_t* U   = u_ch + (size_t)h * 8192;  // [128 batch][64 l]
    const bf16_t* Sch = Sc   + (size_t)h * 8192;  // [128 batch][64 comp]
    const bf16_t* TPh = TP   + (size_t)h * 8192;  // [64 i][128 k]
    f32x4 acc[2][4] = {};
    #pragma unroll
    for (int kk = 0; kk < 4; ++kk) {
        const bf16_t* Ab = (kk < 2) ? (U + kk * 32) : (Sch + (kk - 2) * 32);
        bf16x8 af[2], bfr[4];
        #pragma unroll
        for (int im = 0; im < 2; ++im)
            af[im] = *(const bf16x8*)(Ab + (((w << 1) + im) * 16 + lm) * 64 + ks);
        #pragma unroll
        for (int jn = 0; jn < 4; ++jn)
            bfr[jn] = *(const bf16x8*)(TPh + (jn * 16 + lm) * 128 + kk * 32 + ks);
        #pragma unroll
        for (int im = 0; im < 2; ++im)
            #pragma unroll
            for (int jn = 0; jn < 4; ++jn)
                acc[im][jn] = __builtin_amdgcn_mfma_f32_16x16x32_bf16(
                                  af[im], bfr[jn], acc[im][jn], 0, 0, 0);
    }
    bf16_t* out = y_bi + (size_t)h * 8192;        // [128 batch][64 i]
    const int r4 = (lane >> 4) << 2;
    #pragma unroll
    for (int im = 0; im < 2; ++im)
        #pragma unroll
        for (int jn = 0; jn < 4; ++jn)
            #pragma unroll
            for (int r = 0; r < 4; ++r) {
                int batch = ((w << 1) + im) * 16 + r4 + r;
                int i = jn * 16 + lm;
                out[batch * 64 + i] = (bf16_t)gelu_f(acc[im][jn][r]);
            }
}

// ---------------- 64x64 bf16 tile transpose: dst[c][r] = src[r][c] ------------
__global__ __launch_bounds__(256)
void transpose_kernel(const bf16_t* __restrict__ src, bf16_t* __restrict__ dst,
                      int src_rows, int src_cols)
{
    __shared__ unsigned short tile[64][68];
    const int tid = threadIdx.x;
    const int c0 = blockIdx.x << 6, r0 = blockIdx.y << 6;
    const int r = tid >> 4, c4 = (tid & 15) << 2;
    #pragma unroll
    for (int p = 0; p < 4; ++p) {
        int rr = p * 16 + r;
        ushort4 v = *(const ushort4*)((const unsigned short*)src +
                                      (size_t)(r0 + rr) * src_cols + c0 + c4);
        *(ushort4*)&tile[rr][c4] = v;
    }
    __syncthreads();
    #pragma unroll
    for (int p = 0; p < 4; ++p) {
        int rr = p * 16 + r;                      // dst-row-local (src col)
        ushort4 v;
        v.x = tile[c4 + 0][rr];
        v.y = tile[c4 + 1][rr];
        v.z = tile[c4 + 2][rr];
        v.w = tile[c4 + 3][rr];
        *(ushort4*)((unsigned short*)dst + (size_t)(c0 + rr) * src_rows + r0 + c4) = v;
    }
}

extern "C" void kernel_launch(void* const* d_in, const int* in_sizes, int n_in,
                              void* d_out, int out_size, void* d_ws, size_t ws_size,
                              hipStream_t stream)
{
    (void)in_sizes; (void)n_in; (void)out_size; (void)ws_size;
    const float* x      = (const float*)d_in[0];
    const float* in_W   = (const float*)d_in[1];
    const float* in_b   = (const float*)d_in[2];
    const float* log_dt = (const float*)d_in[3];
    const float* Cp     = (const float*)d_in[4];
    const float* lar    = (const float*)d_in[5];
    const float* aim    = (const float*)d_in[6];
    const float* dsk    = (const float*)d_in[7];
    const float* gluW   = (const float*)d_in[8];
    const float* glub   = (const float*)d_in[9];
    const float* outW   = (const float*)d_in[10];
    const float* outb   = (const float*)d_in[11];

    // ws layout (56.6 MiB peak):
    //  [0,16M):  xb -> TP (after inT) -> y_tok (after g3) -> vb (after z GEMM)
    //  [16,24M): V  -> [16,32M): Sc (after g1)
    //  [16,48M): z (bf16, 32 MB; clobbers Sc + u_ch after both dead)
    //  [32,48M): u_ch (bf16, channel-major)
    //  [48M..):  wbin 2M | wbglu 4M | wbout 2M
    // d_out: Sbc fp32 (32M) -> y_bi bf16 (16M) -> final output
    char* ws = (char*)d_ws;
    bf16_t* xb    = (bf16_t*)(ws);
    bf16_t* TP    = (bf16_t*)(ws);
    bf16_t* y_tok = (bf16_t*)(ws);
    bf16_t* vb    = (bf16_t*)(ws);
    bf16_t* V     = (bf16_t*)(ws + 16777216);
    bf16_t* Sc    = (bf16_t*)(ws + 16777216);
    bf16_t* z     = (bf16_t*)(ws + 16777216);
    bf16_t* u_ch  = (bf16_t*)(ws + 33554432);
    bf16_t* wbin  = (bf16_t*)(ws + 50331648);
    bf16_t* wbglu = (bf16_t*)(ws + 52428800);
    bf16_t* wbout = (bf16_t*)(ws + 56623104);
    float*  Sbc   = (float*)d_out;
    bf16_t* y_bi  = (bf16_t*)d_out;

    f2b_all_kernel<<<dim3(12288), dim3(256), 0, stream>>>(
        x, xb, in_W, wbin, gluW, wbglu, outW, wbout);

    // in-proj, channel-major output: u_ch[h][token]
    gemm_bk64_kernel<0><<<dim3(NTOK / 128, DD / 128), dim3(256), 0, stream>>>(
        wbin, xb, in_b, nullptr, u_ch, NTOK);

    // SSM as per-channel MFMA GEMMs
    genV_kernel <<<dim3(DD / 2), dim3(64), 0, stream>>>(log_dt, lar, aim, V);
    genTP_kernel<<<dim3(DD),     dim3(64), 0, stream>>>(log_dt, lar, aim, Cp, dsk, TP);
    g1_kernel   <<<dim3(DD), dim3(256), 0, stream>>>(u_ch, V, Sbc);
    passB_kernel<<<dim3(DD * BB / 8), dim3(256), 0, stream>>>(Sbc, log_dt, lar, aim, Sc);
    g3_kernel   <<<dim3(DD), dim3(256), 0, stream>>>(u_ch, Sc, TP, y_bi);

    // back to token-major, then GLU (plain N=2048 GEMM + combine) + out-proj
    transpose_kernel<<<dim3(NTOK / 64, DD / 64), dim3(256), 0, stream>>>(y_bi, y_tok, DD, NTOK);
    gemm_bk64_kernel<1><<<dim3(2048 / 128, NTOK / 128), dim3(256), 0, stream>>>(
        y_tok, wbglu, glub, nullptr, z, 2048);
    glu_combine_kernel<<<dim3(NTOK * DD / 8 / 256), dim3(256), 0, stream>>>(z, vb);
    gemm_bk64_kernel<2><<<dim3(DD / 128, NTOK / 128), dim3(256), 0, stream>>>(
        vb, wbout, outb, x, d_out, DD);
}

// Round 8
// 286.162 us; speedup vs baseline: 3.9108x; 1.0820x over previous
//
#include <hip/hip_runtime.h>
#include <math.h>

#define BB 8
#define LL 1024
#define DD 1024
#define KD 1024   // GEMM K depth (token-space GEMMs)
#define NM 32     // complex modes per channel
#define NCH 16    // chunks over L
#define CL 64     // chunk length (NCH*CL == LL)
#define NTOK (BB * LL)

typedef __bf16 bf16_t;
typedef __bf16 bf16x8 __attribute__((ext_vector_type(8)));
typedef __bf16 bf16x4 __attribute__((ext_vector_type(4)));
typedef float  f32x4  __attribute__((ext_vector_type(4)));

__device__ __forceinline__ float gelu_f(float z)
{
    float t = fmaf(0.044715f * z * z, z, z);
    return z / (1.f + expf(-1.5957691216f * t));
}

// ---------------- fused fp32 -> bf16 converts (x, in_W, gluW, outW) -----------
__global__ __launch_bounds__(256)
void f2b_all_kernel(const float* __restrict__ x,    bf16_t* __restrict__ xb,
                    const float* __restrict__ w0,   bf16_t* __restrict__ d0,
                    const float* __restrict__ w1,   bf16_t* __restrict__ d1,
                    const float* __restrict__ w2,   bf16_t* __restrict__ d2)
{
    int b = blockIdx.x;
    const float* s; bf16_t* d; int base;
    if (b < 8192)       { s = x;  d = xb; base = b; }
    else if (b < 9216)  { s = w0; d = d0; base = b - 8192; }
    else if (b < 11264) { s = w1; d = d1; base = b - 9216; }
    else                { s = w2; d = d2; base = b - 11264; }
    int i = (base * 256 + threadIdx.x) * 4;
    float4 f = *(const float4*)(s + i);
    bf16x4 o = { (bf16_t)f.x, (bf16_t)f.y, (bf16_t)f.z, (bf16_t)f.w };
    *(bf16x4*)(d + i) = o;
}

// ---------------- global->LDS staging: 128 rows x 32 bf16 (verified pattern) --
__device__ __forceinline__ void stage128x32(const bf16_t* __restrict__ g,
                                            bf16_t* lds, int tid)
{
    #pragma unroll
    for (int q = 0; q < 2; ++q) {
        const bf16_t* src = g + (size_t)(q * 64 + (tid >> 2)) * KD + (tid & 3) * 8;
        bf16_t* dst = lds + q * 2048 + tid * 8;
        __builtin_amdgcn_global_load_lds(
            (const __attribute__((address_space(1))) void*)src,
            (__attribute__((address_space(3))) void*)dst, 16, 0, 0);
    }
}

// ---------------- BK=64 (2x BK=32 panels) MFMA GEMM + epilogue ----------------
// MODE 0: bf16 out = acc + bias[m]            (in-proj, channel-major out)
// MODE 1: bf16 out = acc + bias[n]            (GLU z)
// MODE 2: f32  out = acc + bias[n] + res[m,n] (out-proj + residual)
template<int MODE>
__global__ __launch_bounds__(256)
void gemm_bk64_kernel(const bf16_t* __restrict__ A, const bf16_t* __restrict__ B,
                      const float* __restrict__ bias, const float* __restrict__ res,
                      void* __restrict__ outp, int ldo)
{
    __shared__ bf16_t As[2][128 * 32];
    __shared__ bf16_t Bs[2][128 * 32];
    const int tid = threadIdx.x;
    const int lane = tid & 63, w = tid >> 6;
    const int wy = w >> 1, wx = w & 1;
    const int m0 = blockIdx.y << 7, n0 = blockIdx.x << 7;
    const bf16_t* Ag = A + (size_t)m0 * KD;
    const bf16_t* Bg = B + (size_t)n0 * KD;
    f32x4 acc[4][4] = {};
    const int lm = lane & 15;
    const int ks = (lane >> 4) << 3;

    for (int k0 = 0; k0 < KD; k0 += 64) {
        stage128x32(Ag + k0,      As[0], tid);
        stage128x32(Bg + k0,      Bs[0], tid);
        stage128x32(Ag + k0 + 32, As[1], tid);
        stage128x32(Bg + k0 + 32, Bs[1], tid);
        __syncthreads();
        #pragma unroll
        for (int p = 0; p < 2; ++p) {
            bf16x8 af[4], bfr[4];
            #pragma unroll
            for (int i = 0; i < 4; ++i)
                af[i] = *(bf16x8*)&As[p][((wy << 6) + (i << 4) + lm) * 32 + ks];
            #pragma unroll
            for (int j = 0; j < 4; ++j)
                bfr[j] = *(bf16x8*)&Bs[p][((wx << 6) + (j << 4) + lm) * 32 + ks];
            #pragma unroll
            for (int i = 0; i < 4; ++i)
                #pragma unroll
                for (int j = 0; j < 4; ++j)
                    acc[i][j] = __builtin_amdgcn_mfma_f32_16x16x32_bf16(
                                    af[i], bfr[j], acc[i][j], 0, 0, 0);
        }
        __syncthreads();
    }

    const int row4 = (lane >> 4) << 2;
    #pragma unroll
    for (int i = 0; i < 4; ++i) {
        #pragma unroll
        for (int r = 0; r < 4; ++r) {
            int m = m0 + (wy << 6) + (i << 4) + row4 + r;
            #pragma unroll
            for (int j = 0; j < 4; ++j) {
                int n = n0 + (wx << 6) + (j << 4) + lm;
                float v = acc[i][j][r];
                if (MODE == 0) {
                    ((bf16_t*)outp)[(size_t)m * ldo + n] = (bf16_t)(v + bias[m]);
                } else if (MODE == 1) {
                    ((bf16_t*)outp)[(size_t)m * ldo + n] = (bf16_t)(v + bias[n]);
                } else {
                    ((float*)outp)[(size_t)m * ldo + n] =
                        v + bias[n] + res[(size_t)m * ldo + n];
                }
            }
        }
    }
}

// ---------------- GLU combine: v = za * sigmoid(zg), bf16 ---------------------
__global__ __launch_bounds__(256)
void glu_combine_kernel(const bf16_t* __restrict__ z, bf16_t* __restrict__ v)
{
    int i = blockIdx.x * 256 + threadIdx.x;       // one thread = 8 elements
    int m = i >> 7, n8 = (i & 127) << 3;
    const bf16_t* zp = z + (size_t)m * 2048 + n8;
    bf16x8 za = *(const bf16x8*)zp;
    bf16x8 zg = *(const bf16x8*)(zp + 1024);
    bf16x8 o;
    #pragma unroll
    for (int e = 0; e < 8; ++e) {
        float a = (float)za[e], gg = (float)zg[e];
        o[e] = (bf16_t)(a / (1.f + expf(-gg)));
    }
    *(bf16x8*)(v + (size_t)m * 1024 + n8) = o;
}

// ---------------- genV + genTP merged (block-uniform branch) ------------------
// blocks [0, DD/2): V[h][comp][l] = Re/Im(w^(63-l));  blocks [DD/2, DD/2+DD): TP
__global__ __launch_bounds__(64)
void genVTP_kernel(const float* __restrict__ log_dt, const float* __restrict__ lar,
                   const float* __restrict__ aim, const float* __restrict__ Cp,
                   const float* __restrict__ dskip,
                   bf16_t* __restrict__ V, bf16_t* __restrict__ TP)
{
    const int tid = threadIdx.x;
    if (blockIdx.x < DD / 2) {
        const int h = blockIdx.x * 2 + (tid >> 5);
        const int n = tid & 31;
        const float dt = expf(log_dt[h]);
        const float ardt = -expf(lar[h * NM + n]) * dt;
        const float aidt = aim[h * NM + n] * dt;
        float sn, cs;
        sincosf(aidt, &sn, &cs);
        float er = expf(ardt);
        float wr = er * cs, wi = er * sn;
        float inv = 1.f / fmaf(wr, wr, wi * wi);
        float vr = wr * inv, vi = -wi * inv;      // w^-1
        sincosf(63.f * aidt, &sn, &cs);
        er = expf(63.f * ardt);
        float pr = er * cs, pi = er * sn;         // w^63
        bf16_t* rowr = V + ((size_t)h * 64 + 2 * n) * 64;
        bf16_t* rowi = rowr + 64;
        #pragma unroll
        for (int c8 = 0; c8 < 8; ++c8) {
            bf16x8 rr, ri;
            #pragma unroll
            for (int e = 0; e < 8; ++e) {
                rr[e] = (bf16_t)pr; ri[e] = (bf16_t)pi;
                float t = fmaf(pr, vr, -pi * vi);
                pi = fmaf(pr, vi, pi * vr);
                pr = t;
            }
            *(bf16x8*)(rowr + c8 * 8) = rr;
            *(bf16x8*)(rowi + c8 * 8) = ri;
        }
        return;
    }
    // ---- TP branch ----
    __shared__ float ardt_s[NM], aidt_s[NM], cr_s[NM], ci_s[NM], K_s[CL];
    const int h = blockIdx.x - DD / 2;
    const float dt = expf(log_dt[h]);
    if (tid < NM) {
        int n = tid;
        float ar = -expf(lar[h * NM + n]);
        float ai = aim[h * NM + n];
        float sn, cs;
        sincosf(ai * dt, &sn, &cs);
        float er = expf(ar * dt);
        float wrr = er * cs, wii = er * sn;
        float Crr = Cp[(h * NM + n) * 2 + 0];
        float Cii = Cp[(h * NM + n) * 2 + 1];
        float nr = fmaf(Crr, wrr - 1.f, -Cii * wii);
        float ni = fmaf(Crr, wii, Cii * (wrr - 1.f));
        float inv = 2.f / fmaf(ar, ar, ai * ai);
        cr_s[n] = fmaf(nr, ar, ni * ai) * inv;
        ci_s[n] = fmaf(ni, ar, -nr * ai) * inv;
        ardt_s[n] = ar * dt;
        aidt_s[n] = ai * dt;
    }
    __syncthreads();
    {   // K[d] = sum_n cr*Re(w^d) - ci*Im(w^d);  K[0] += D_skip
        float d = (float)tid;
        float kv = (tid == 0) ? dskip[h] : 0.f;
        #pragma unroll 8
        for (int n = 0; n < NM; ++n) {
            float sn, cs;
            sincosf(aidt_s[n] * d, &sn, &cs);
            float e = expf(ardt_s[n] * d);
            kv = fmaf(cr_s[n], e * cs, kv);
            kv = fmaf(-ci_s[n], e * sn, kv);
        }
        K_s[tid] = kv;
    }
    __syncthreads();
    const int i = tid;
    bf16_t* row = TP + ((size_t)h * CL + i) * 128;
    #pragma unroll
    for (int c8 = 0; c8 < 8; ++c8) {
        bf16x8 v;
        #pragma unroll
        for (int e = 0; e < 8; ++e) {
            int l = c8 * 8 + e;
            v[e] = (l <= i) ? (bf16_t)K_s[i - l] : (bf16_t)0.f;
        }
        *(bf16x8*)(row + c8 * 8) = v;
    }
    const float fi = (float)(i + 1);
    #pragma unroll
    for (int c8 = 0; c8 < 8; ++c8) {
        bf16x8 v;
        #pragma unroll
        for (int q = 0; q < 4; ++q) {
            int n = c8 * 4 + q;
            float sn, cs;
            sincosf(aidt_s[n] * fi, &sn, &cs);
            float e = expf(ardt_s[n] * fi);
            float Wr = e * cs, Wi = e * sn;
            v[2 * q]     = (bf16_t)(fmaf(cr_s[n], Wr, -ci_s[n] * Wi));
            v[2 * q + 1] = (bf16_t)(-fmaf(cr_s[n], Wi, ci_s[n] * Wr));
        }
        *(bf16x8*)(row + 64 + c8 * 8) = v;
    }
}

// ---------------- fused SSM: S=U@V^T -> scan (LDS) -> Y=[U|Sc]@TP^T, gelu -----
// One block per channel h. 256 threads = 4 waves; wave w owns batch groups
// 2w, 2w+1 (16 rows each). LDS: Sbc fp32 32 KB + Sc bf16 16 KB.
__global__ __launch_bounds__(256)
void ssm_fused_kernel(const bf16_t* __restrict__ u_ch, const bf16_t* __restrict__ V,
                      const bf16_t* __restrict__ TP,
                      const float* __restrict__ log_dt, const float* __restrict__ lar,
                      const float* __restrict__ aim, bf16_t* __restrict__ y_bi)
{
    __shared__ float  Sbc_s[128 * 64];
    __shared__ bf16_t Sc_s[128 * 64];
    const int h = blockIdx.x;
    const int tid = threadIdx.x;
    const int lane = tid & 63, w = tid >> 6;
    const int lm = lane & 15, ks = (lane >> 4) << 3;
    const bf16_t* U   = u_ch + (size_t)h * 8192;  // [128 batch][64 l]
    const bf16_t* Vh  = V    + (size_t)h * 4096;  // [64 comp][64 l]
    const bf16_t* TPh = TP   + (size_t)h * 8192;  // [64 i][128 k]

    // U fragments, loaded once, reused for both MFMAs
    bf16x8 af_u[2][2];
    #pragma unroll
    for (int im = 0; im < 2; ++im)
        #pragma unroll
        for (int kk = 0; kk < 2; ++kk)
            af_u[im][kk] = *(const bf16x8*)(U + (((w << 1) + im) * 16 + lm) * 64
                                            + kk * 32 + ks);

    // ---- G1: chunk-local end states ----
    f32x4 acc1[2][4] = {};
    #pragma unroll
    for (int kk = 0; kk < 2; ++kk) {
        bf16x8 bfr[4];
        #pragma unroll
        for (int jn = 0; jn < 4; ++jn)
            bfr[jn] = *(const bf16x8*)(Vh + (jn * 16 + lm) * 64 + kk * 32 + ks);
        #pragma unroll
        for (int im = 0; im < 2; ++im)
            #pragma unroll
            for (int jn = 0; jn < 4; ++jn)
                acc1[im][jn] = __builtin_amdgcn_mfma_f32_16x16x32_bf16(
                                   af_u[im][kk], bfr[jn], acc1[im][jn], 0, 0, 0);
    }
    const int r4 = (lane >> 4) << 2;
    #pragma unroll
    for (int im = 0; im < 2; ++im)
        #pragma unroll
        for (int jn = 0; jn < 4; ++jn)
            #pragma unroll
            for (int r = 0; r < 4; ++r)
                Sbc_s[(((w << 1) + im) * 16 + r4 + r) * 64 + jn * 16 + lm]
                    = acc1[im][jn][r];
    __syncthreads();

    // ---- scan over chunks: thread t -> (b = t>>5, n = t&31) ----
    {
        const int b = tid >> 5, n = tid & 31;
        const float dtv = expf(log_dt[h]);
        const float ardt = -expf(lar[h * NM + n]) * dtv;
        const float aidt = aim[h * NM + n] * dtv;
        float sn, cs;
        sincosf(64.f * aidt, &sn, &cs);
        float er = expf(64.f * ardt);
        const float gr = er * cs, gi = er * sn;   // w^CL
        float sr = 0.f, si = 0.f;
        for (int c = 0; c < NCH; ++c) {
            int idx = (b * 16 + c) * 64 + 2 * n;
            float lr = Sbc_s[idx], li = Sbc_s[idx + 1];
            Sc_s[idx]     = (bf16_t)sr;           // carry-in state for chunk c
            Sc_s[idx + 1] = (bf16_t)si;
            float t0 = fmaf(gr, sr, fmaf(-gi, si, lr));
            si = fmaf(gr, si, fmaf(gi, sr, li));
            sr = t0;
        }
    }
    __syncthreads();

    // ---- G3: Y = [U | Sc] @ TP^T, gelu ----
    f32x4 acc2[2][4] = {};
    #pragma unroll
    for (int kk = 0; kk < 4; ++kk) {
        bf16x8 af[2], bfr[4];
        #pragma unroll
        for (int im = 0; im < 2; ++im) {
            if (kk < 2)
                af[im] = af_u[im][kk];
            else
                af[im] = *(bf16x8*)&Sc_s[(((w << 1) + im) * 16 + lm) * 64
                                         + (kk - 2) * 32 + ks];
        }
        #pragma unroll
        for (int jn = 0; jn < 4; ++jn)
            bfr[jn] = *(const bf16x8*)(TPh + (jn * 16 + lm) * 128 + kk * 32 + ks);
        #pragma unroll
        for (int im = 0; im < 2; ++im)
            #pragma unroll
            for (int jn = 0; jn < 4; ++jn)
                acc2[im][jn] = __builtin_amdgcn_mfma_f32_16x16x32_bf16(
                                   af[im], bfr[jn], acc2[im][jn], 0, 0, 0);
    }
    bf16_t* out = y_bi + (size_t)h * 8192;        // [128 batch][64 i]
    #pragma unroll
    for (int im = 0; im < 2; ++im)
        #pragma unroll
        for (int jn = 0; jn < 4; ++jn)
            #pragma unroll
            for (int r = 0; r < 4; ++r) {
                int batch = ((w << 1) + im) * 16 + r4 + r;
                int i = jn * 16 + lm;
                out[batch * 64 + i] = (bf16_t)gelu_f(acc2[im][jn][r]);
            }
}

// ---------------- 64x64 bf16 tile transpose: dst[c][r] = src[r][c] ------------
__global__ __launch_bounds__(256)
void transpose_kernel(const bf16_t* __restrict__ src, bf16_t* __restrict__ dst,
                      int src_rows, int src_cols)
{
    __shared__ unsigned short tile[64][68];
    const int tid = threadIdx.x;
    const int c0 = blockIdx.x << 6, r0 = blockIdx.y << 6;
    const int r = tid >> 4, c4 = (tid & 15) << 2;
    #pragma unroll
    for (int p = 0; p < 4; ++p) {
        int rr = p * 16 + r;
        ushort4 v = *(const ushort4*)((const unsigned short*)src +
                                      (size_t)(r0 + rr) * src_cols + c0 + c4);
        *(ushort4*)&tile[rr][c4] = v;
    }
    __syncthreads();
    #pragma unroll
    for (int p = 0; p < 4; ++p) {
        int rr = p * 16 + r;                      // dst-row-local (src col)
        ushort4 v;
        v.x = tile[c4 + 0][rr];
        v.y = tile[c4 + 1][rr];
        v.z = tile[c4 + 2][rr];
        v.w = tile[c4 + 3][rr];
        *(ushort4*)((unsigned short*)dst + (size_t)(c0 + rr) * src_rows + r0 + c4) = v;
    }
}

extern "C" void kernel_launch(void* const* d_in, const int* in_sizes, int n_in,
                              void* d_out, int out_size, void* d_ws, size_t ws_size,
                              hipStream_t stream)
{
    (void)in_sizes; (void)n_in; (void)out_size; (void)ws_size;
    const float* x      = (const float*)d_in[0];
    const float* in_W   = (const float*)d_in[1];
    const float* in_b   = (const float*)d_in[2];
    const float* log_dt = (const float*)d_in[3];
    const float* Cp     = (const float*)d_in[4];
    const float* lar    = (const float*)d_in[5];
    const float* aim    = (const float*)d_in[6];
    const float* dsk    = (const float*)d_in[7];
    const float* gluW   = (const float*)d_in[8];
    const float* glub   = (const float*)d_in[9];
    const float* outW   = (const float*)d_in[10];
    const float* outb   = (const float*)d_in[11];

    // ws layout (56.6 MiB peak):
    //  [0,16M):  xb -> TP (after in-proj) -> y_tok (after ssm) -> vb (after z GEMM)
    //  [16,24M): V  -> [16,48M): z (after ssm; clobbers V + u_ch, both dead)
    //  [32,48M): u_ch (bf16, channel-major)
    //  [48M..):  wbin 2M | wbglu 4M | wbout 2M
    // d_out: y_bi bf16 (16M) -> final output
    char* ws = (char*)d_ws;
    bf16_t* xb    = (bf16_t*)(ws);
    bf16_t* TP    = (bf16_t*)(ws);
    bf16_t* y_tok = (bf16_t*)(ws);
    bf16_t* vb    = (bf16_t*)(ws);
    bf16_t* V     = (bf16_t*)(ws + 16777216);
    bf16_t* z     = (bf16_t*)(ws + 16777216);
    bf16_t* u_ch  = (bf16_t*)(ws + 33554432);
    bf16_t* wbin  = (bf16_t*)(ws + 50331648);
    bf16_t* wbglu = (bf16_t*)(ws + 52428800);
    bf16_t* wbout = (bf16_t*)(ws + 56623104);
    bf16_t* y_bi  = (bf16_t*)d_out;

    f2b_all_kernel<<<dim3(12288), dim3(256), 0, stream>>>(
        x, xb, in_W, wbin, gluW, wbglu, outW, wbout);

    // in-proj, channel-major output: u_ch[h][token]
    gemm_bk64_kernel<0><<<dim3(NTOK / 128, DD / 128), dim3(256), 0, stream>>>(
        wbin, xb, in_b, nullptr, u_ch, NTOK);

    // SSM: param tables, then fused per-channel (G1 -> scan -> G3)
    genVTP_kernel<<<dim3(DD / 2 + DD), dim3(64), 0, stream>>>(
        log_dt, lar, aim, Cp, dsk, V, TP);
    ssm_fused_kernel<<<dim3(DD), dim3(256), 0, stream>>>(
        u_ch, V, TP, log_dt, lar, aim, y_bi);

    // back to token-major, then GLU (plain N=2048 GEMM + combine) + out-proj
    transpose_kernel<<<dim3(NTOK / 64, DD / 64), dim3(256), 0, stream>>>(y_bi, y_tok, DD, NTOK);
    gemm_bk64_kernel<1><<<dim3(2048 / 128, NTOK / 128), dim3(256), 0, stream>>>(
        y_tok, wbglu, glub, nullptr, z, 2048);
    glu_combine_kernel<<<dim3(NTOK * DD / 8 / 256), dim3(256), 0, stream>>>(z, vb);
    gemm_bk64_kernel<2><<<dim3(DD / 128, NTOK / 128), dim3(256), 0, stream>>>(
        vb, wbout, outb, x, d_out, DD);
}